// Round 13
// baseline (527.564 us; speedup 1.0000x reference)
//
#include <hip/hip_runtime.h>
#include <cstdint>
#include <cstddef>

// DGCNN forward. R24: column-split halves + exact rank merge.
// R23's fused kernel: 131KB LDS -> 1 block/CU, strict two-phase structure ->
// ~40us/dispatch of naked latency (compute mem-latency, select chain-latency;
// all waves always in the SAME phase). R24 splits each 16-row tile into two
// 1024-col half-blocks (64KB keys) -> 2 blocks/CU: co-resident blocks overlap
// select(VALU) with compute(MFMA/mem) WITHOUT R22's MFMA doubling (each block
// does half the j-range; total MFMA unchanged). Each half selects its exact
// top-20 (global top-20 is a subset of the union) and emits (distkey,col) u64
// candidates; knn_merge ranks 40 candidates/row by count-greater (no dependent
// rounds) with exact lowest-col tie-break == top_k. Keys pack 4 pos bits (less
// truncation than R23). 16-col-segment swizzle: phys=(c&~15)|((c+(c>>6))&15).

constexpr int NB = 8;
constexpr int NP = 2048;
constexpr int KK = 20;

typedef short bf16x8 __attribute__((ext_vector_type(8)));
typedef float f32x16 __attribute__((ext_vector_type(16)));
typedef float f32x4 __attribute__((ext_vector_type(4)));

__device__ __forceinline__ f32x16 MF(bf16x8 a, bf16x8 b, f32x16 c) {
  return __builtin_amdgcn_mfma_f32_32x32x16_bf16(a, b, c, 0, 0, 0);
}
__device__ __forceinline__ f32x4 MF16(bf16x8 a, bf16x8 b, f32x4 c) {
  return __builtin_amdgcn_mfma_f32_16x16x32_bf16(a, b, c, 0, 0, 0);
}
__device__ __forceinline__ unsigned short bfh(float f) {
  return (unsigned short)(__float_as_uint(f) >> 16);  // truncating bf16
}
__device__ __forceinline__ float bff(unsigned short u) {
  return __uint_as_float(((unsigned)u) << 16);
}
__device__ __forceinline__ void split2(float v, unsigned short& h, unsigned short& l) {
  h = bfh(v); l = bfh(v - bff(h));
}
// local-column swizzle for 16-col segments: seg = c>>4, rot by seg>>2.
__device__ __forceinline__ int PHYS(int c) {
  return (c & ~15) | ((c + (c >> 6)) & 15);
}
// monotone key with 4 position bits (m = local col & 15).
__device__ __forceinline__ unsigned packkey(float d, int m) {
  const unsigned u = __float_as_uint(d);
  const unsigned k = (u & 0x80000000u) ? ~u : (u | 0x80000000u);
  return (k & ~15u) | (15u - (unsigned)m);
}

// full-wave unsigned max via DPP (identity 0); uniform result in all lanes.
__device__ __forceinline__ unsigned wavemaxu(unsigned v) {
  int x = (int)v, t;
  t = __builtin_amdgcn_update_dpp(0, x, 0x111, 0xf, 0xf, false);  // row_shr:1
  x = (int)(((unsigned)x > (unsigned)t) ? (unsigned)x : (unsigned)t);
  t = __builtin_amdgcn_update_dpp(0, x, 0x112, 0xf, 0xf, false);  // row_shr:2
  x = (int)(((unsigned)x > (unsigned)t) ? (unsigned)x : (unsigned)t);
  t = __builtin_amdgcn_update_dpp(0, x, 0x114, 0xf, 0xf, false);  // row_shr:4
  x = (int)(((unsigned)x > (unsigned)t) ? (unsigned)x : (unsigned)t);
  t = __builtin_amdgcn_update_dpp(0, x, 0x118, 0xf, 0xf, false);  // row_shr:8
  x = (int)(((unsigned)x > (unsigned)t) ? (unsigned)x : (unsigned)t);
  t = __builtin_amdgcn_update_dpp(0, x, 0x142, 0xf, 0xf, false);  // row_bcast15
  x = (int)(((unsigned)x > (unsigned)t) ? (unsigned)x : (unsigned)t);
  t = __builtin_amdgcn_update_dpp(0, x, 0x143, 0xf, 0xf, false);  // row_bcast31
  x = (int)(((unsigned)x > (unsigned)t) ? (unsigned)x : (unsigned)t);
  return (unsigned)__builtin_amdgcn_readlane(x, 63);
}

// ---------------- pad x -> x4, plus L0 norms ----------------
__global__ __launch_bounds__(256) void pad_norms(const float* __restrict__ x,
    float* __restrict__ x4, float* __restrict__ nrm) {
  const int p = blockIdx.x * 256 + threadIdx.x;  // 16384
  float4 v;
  v.x = x[p * 3 + 0]; v.y = x[p * 3 + 1]; v.z = x[p * 3 + 2]; v.w = 0.f;
  *reinterpret_cast<float4*>(x4 + (size_t)p * 4) = v;
  nrm[p] = v.x * v.x + v.y * v.y + v.z * v.z;
}

// ---------------- all weight splits, fragment-order output ----------------
__global__ __launch_bounds__(256) void wsplit_all(const float* __restrict__ W1,
    const float* __restrict__ W2, const float* __restrict__ W3,
    const float* __restrict__ Wf,
    unsigned short* __restrict__ wb1, unsigned short* __restrict__ wb2,
    unsigned short* __restrict__ wb3,
    unsigned short* __restrict__ wfh, unsigned short* __restrict__ wfl) {
  const int id = blockIdx.x * 256 + threadIdx.x;  // 569344 total
  if (id < 524288) {
    const int row = id >> 9, c = id & 511;
    unsigned short h, l;
    split2(Wf[id], h, l);
    const size_t a = ((((size_t)(row >> 6)) * 64 + (c >> 3)) * 64 + (row & 63)) * 8 + (c & 7);
    wfh[a] = h; wfl[a] = l;
    return;
  }
  int id2 = id - 524288;
  const float* W; unsigned short* wb; int O, C;
  if (id2 < 4096)      { W = W1; wb = wb1; O = 64;  C = 64;  }
  else if (id2 < 12288){ W = W2; wb = wb2; O = 128; C = 64;  id2 -= 4096; }
  else                 { W = W3; wb = wb3; O = 256; C = 128; id2 -= 12288; }
  const int o = id2 / C, c = id2 % C;
  const int K8 = C >> 3;
  const float w1 = W[o * 2 * C + c];
  const float w2 = W[o * 2 * C + C + c];
  unsigned short h, l;
  const int r1 = o, rd = O + o;
  const size_t a1 = (((size_t)(r1 >> 6) * K8 + (c >> 3)) * 64 + (r1 & 63)) * 8 + (c & 7);
  const size_t ad = (((size_t)(rd >> 6) * K8 + (c >> 3)) * 64 + (rd & 63)) * 8 + (c & 7);
  split2(w1, h, l);
  wb[a1] = h; wb[2 * O * C + a1] = l;
  split2(w2 - w1, h, l);
  wb[ad] = h; wb[2 * O * C + ad] = l;
}

// ---------------- half-row top-20 select on packed keys -> candidates -----------
// Lane owns local cols [lane*16, lane*16+16) of the 1024-col half. Winner col
// uniform from (wm,wl); lane-0 poke; fenced cooperative refill. Emits 20
// (distkey,col) u64 candidates: M = (key&~15)<<32 | (4095-globalcol) so u64
// order = distance desc, then lowest col (== top_k tie-break).
__device__ __forceinline__ void select20h(unsigned* __restrict__ srow,
    const int lane, const int jh, unsigned long long* __restrict__ candrow) {
  const int i15 = lane & 15;
  const int rot = lane >> 2;
  unsigned k1 = 0u, k2 = 0u;
#pragma unroll
  for (int m = 0; m < 16; ++m) {
    const unsigned e = srow[lane * 16 + ((m + rot) & 15)];
    const unsigned lo = (k1 < e) ? k1 : e;
    k1 = (k1 > e) ? k1 : e;
    k2 = (k2 > lo) ? k2 : lo;
  }
  unsigned mykey = 0u; int mycol = 0;
#pragma unroll
  for (int r = 0; r < KK; ++r) {
    const unsigned wm = wavemaxu(k1);
    const unsigned long long bal = __ballot(k1 == wm);
    const int wl = bal ? (__ffsll(bal) - 1) : 0;
    const int mwin = 15 - (int)(wm & 15u);
    if (lane == r) { mykey = wm; mycol = wl * 16 + mwin; }
    if (lane == 0) srow[wl * 16 + ((mwin + (wl >> 2)) & 15)] = 0u;  // poke
    if (lane == wl) { k1 = k2; k2 = 0u; }
    if (__ballot(k1 == 0u)) {  // a twice-popped winner needs refill
      asm volatile("s_waitcnt lgkmcnt(0)" ::: "memory");  // drain pokes
      __builtin_amdgcn_sched_barrier(0);                  // rule #18 fence
      const unsigned e = srow[wl * 16 + ((i15 + (wl >> 2)) & 15)];
      const unsigned nm = wavemaxu(e);
      if (lane == wl) k1 = nm;
    }
  }
  if (lane < KK) {
    const int gcol = jh * 1024 + mycol;
    const unsigned long long M =
        (((unsigned long long)(mykey & ~15u)) << 32) | (unsigned long long)(4095 - gcol);
    candrow[lane] = M;
  }
}

// ---------------- merge: exact top-20 of 40 candidates by rank ----------------
__global__ __launch_bounds__(256) void knn_merge(const unsigned long long* __restrict__ cand,
    int* __restrict__ idxout) {
  __shared__ unsigned long long sc[4][40];
  const int t = threadIdx.x, lane = t & 63, w = t >> 6;
  const int row = blockIdx.x * 4 + w;  // 16384 rows
  unsigned long long mine = 0ull;
  if (lane < 40) {
    mine = cand[(size_t)row * 40 + lane];
    sc[w][lane] = mine;
  }
  asm volatile("s_waitcnt lgkmcnt(0)" ::: "memory");
  __builtin_amdgcn_sched_barrier(0);
  if (lane < 40) {
    int rank = 0;
#pragma unroll
    for (int j = 0; j < 40; ++j) rank += (sc[w][j] > mine) ? 1 : 0;
    if (rank < KK)
      idxout[(size_t)row * KK + rank] = 4095 - (int)(mine & 4095ull);
  }
}

// ---------------- fused dist+knn, L0 (C=3, fp32), half-column blocks ------------
__global__ __launch_bounds__(1024, 8) void fused_dist_knn0(const float* __restrict__ X4,
    const float* __restrict__ norms, unsigned long long* __restrict__ cand) {
  __shared__ unsigned sdist[16][1024];
  const int t = threadIdx.x, lane = t & 63, w = t >> 6;  // w: 0..15
  const int l15 = lane & 15, g4 = lane >> 4;
  const int bid = blockIdx.x;          // 2048
  const int b = bid & 7;               // XCD-batch affinity
  const int gg = bid >> 3;             // 0..255
  const int tile = gg >> 1, jh = gg & 1;
  const int i0 = tile * 16;

  float4 rx[4]; float ni[4];
#pragma unroll
  for (int e = 0; e < 4; ++e) {
    const int p = b * NP + i0 + g4 * 4 + e;
    rx[e] = *reinterpret_cast<const float4*>(X4 + (size_t)p * 4);
    ni[e] = norms[p];
  }

#pragma unroll
  for (int it = 0; it < 4; ++it) {
    const int jl = it * 256 + w * 16 + l15;       // local col 0..1023
    const int p = b * NP + jh * 1024 + jl;
    const float4 cj = *reinterpret_cast<const float4*>(X4 + (size_t)p * 4);
    const float nj = norms[p];
    const int ps = PHYS(jl);
#pragma unroll
    for (int e = 0; e < 4; ++e) {
      float acc = fmaf(rx[e].x, cj.x, 0.f);
      acc = fmaf(rx[e].y, cj.y, acc);
      acc = fmaf(rx[e].z, cj.z, acc);
      sdist[g4 * 4 + e][ps] = packkey(2.f * acc - ni[e] - nj, jl & 15);
    }
  }
  __syncthreads();

  const int row = b * NP + i0 + w;
  select20h(&sdist[w][0], lane, jh, cand + ((size_t)row * 2 + jh) * KK);
}

// ---------------- fused dist+knn (l>=1): MFMA 16x16x32, half-column blocks ------
template<int C>
__global__ __launch_bounds__(1024, 8) void fused_dist_knn(const unsigned short* __restrict__ xh,
    const unsigned short* __restrict__ xl, int colbase,
    const float* __restrict__ norms, unsigned long long* __restrict__ cand) {
  constexpr int KB = C / 32;  // K-blocks per chain
  __shared__ unsigned sdist[16][1024];
  const int t = threadIdx.x, lane = t & 63, w = t >> 6;  // w: 0..15
  const int l15 = lane & 15, g4 = lane >> 4;
  const int bid = blockIdx.x;          // 2048
  const int b = bid & 7;               // XCD-batch affinity
  const int gg = bid >> 3;             // 0..255
  const int tile = gg >> 1, jh = gg & 1;
  const int i0 = tile * 16;
  const int ti = (b * NP + i0) >> 6;
  const int ir = i0 & 63;
  const int k8b = colbase >> 3;

  bf16x8 AH[KB], AL[KB];
#pragma unroll
  for (int kb = 0; kb < KB; ++kb) {
    const size_t a = (((size_t)ti * 64 + k8b + kb * 4 + g4) * 64 + ir + l15) * 8;
    AH[kb] = *reinterpret_cast<const bf16x8*>(xh + a);
    AL[kb] = *reinterpret_cast<const bf16x8*>(xl + a);
  }
  float ni[4];
#pragma unroll
  for (int e = 0; e < 4; ++e) ni[e] = norms[b * NP + i0 + g4 * 4 + e];

#pragma unroll
  for (int it = 0; it < 4; ++it) {
    const int j0 = it * 256 + w * 16;             // local col base
    const int jg = jh * 1024 + j0;                // global col base
    const int tj = (b * NP + jg) >> 6;
    const int jr = jg & 63;
    bf16x8 BH[KB], BL[KB];
#pragma unroll
    for (int kb = 0; kb < KB; ++kb) {
      const size_t a = (((size_t)tj * 64 + k8b + kb * 4 + g4) * 64 + jr + l15) * 8;
      BH[kb] = *reinterpret_cast<const bf16x8*>(xh + a);
      BL[kb] = *reinterpret_cast<const bf16x8*>(xl + a);
    }
    f32x4 acc = {0.f, 0.f, 0.f, 0.f};
#pragma unroll
    for (int kb = 0; kb < KB; ++kb) {
      acc = MF16(AH[kb], BH[kb], acc);
      acc = MF16(AH[kb], BL[kb], acc);
      acc = MF16(AL[kb], BH[kb], acc);
    }
    const float nj = norms[b * NP + jg + l15];
    const int ps = PHYS(j0 + l15);
#pragma unroll
    for (int e = 0; e < 4; ++e)
      sdist[g4 * 4 + e][ps] = packkey(2.f * acc[e] - ni[e] - nj, l15);
  }
  __syncthreads();

  const int row = b * NP + i0 + w;
  select20h(&sdist[w][0], lane, jh, cand + ((size_t)row * 2 + jh) * KK);
}

// ---------------- per-point GEMM, L0 (C=3, fp32 vector) ----------------
__global__ __launch_bounds__(256) void pt_gemm0(const float* __restrict__ x,
    const float* __restrict__ W, const float* __restrict__ bias,
    float* __restrict__ Y, float* __restrict__ T) {
  const int t = threadIdx.x;
  const int o = t & 63;
  const int g = blockIdx.x * 4 + (t >> 6);  // 0..16383
  const float x0 = x[(size_t)g * 3 + 0], x1 = x[(size_t)g * 3 + 1], x2 = x[(size_t)g * 3 + 2];
  const float w10 = W[o * 6 + 0], w11 = W[o * 6 + 1], w12 = W[o * 6 + 2];
  const float w20 = W[o * 6 + 3], w21 = W[o * 6 + 4], w22 = W[o * 6 + 5];
  Y[(size_t)g * 64 + o] = w10 * x0 + w11 * x1 + w12 * x2;
  T[(size_t)g * 64 + o] = (w20 - w10) * x0 + (w21 - w11) * x1 + (w22 - w12) * x2 + bias[o];
}

// ---------------- per-point GEMM (l>=1): LDS-free, [Y||T] = X Wcat^T ----------------
template<int C, int O2>  // O2 = 2*O
__global__ __launch_bounds__(256) void pt_gemm(const unsigned short* __restrict__ xh,
    const unsigned short* __restrict__ xl, int colbase,
    const unsigned short* __restrict__ wch, const unsigned short* __restrict__ wcl,
    const float* __restrict__ bias, float* __restrict__ Y, float* __restrict__ T) {
  constexpr int K8 = C / 8;
  constexpr int H = K8 / 2;
  constexpr int O = O2 / 2;
  const int t = threadIdx.x, lane = t & 63, w = t >> 6;
  const int half = lane >> 5, l31 = lane & 31;
  const int rt = (w >> 1) * 32, tc = (w & 1) * 32;
  const int n0 = blockIdx.x * 64, o0 = blockIdx.y * 64;
  const int tn = n0 >> 6, to = o0 >> 6;
  const int k8b = colbase >> 3;
  const int col = o0 + tc + l31;

  bf16x8 BH[H], BL[H];
#pragma unroll
  for (int ch = 0; ch < H; ++ch) {
    const size_t a = (((size_t)to * K8 + ch * 2 + half) * 64 + tc + l31) * 8;
    BH[ch] = *reinterpret_cast<const bf16x8*>(wch + a);
    BL[ch] = *reinterpret_cast<const bf16x8*>(wcl + a);
  }

  f32x16 acc;
#pragma unroll
  for (int i = 0; i < 16; ++i) acc[i] = 0.f;
#pragma unroll
  for (int ch = 0; ch < H; ++ch) {
    const size_t a = (((size_t)tn * 64 + k8b + ch * 2 + half) * 64 + rt + l31) * 8;
    const bf16x8 ah = *reinterpret_cast<const bf16x8*>(xh + a);
    const bf16x8 al = *reinterpret_cast<const bf16x8*>(xl + a);
    acc = MF(ah, BH[ch], acc); acc = MF(ah, BL[ch], acc); acc = MF(al, BH[ch], acc);
  }

  if (col < O) {
#pragma unroll
    for (int i = 0; i < 16; ++i) {
      const int row = n0 + rt + (i & 3) + 8 * (i >> 2) + 4 * half;
      Y[(size_t)row * O + col] = acc[i];
    }
  } else {
    const float bv = bias[col - O];
#pragma unroll
    for (int i = 0; i < 16; ++i) {
      const int row = n0 + rt + (i & 3) + 8 * (i >> 2) + 4 * half;
      T[(size_t)row * O + (col - O)] = acc[i] + bv;
    }
  }
}

// ---------------- edge reduce: max/sum/sumsq over gathered Y rows ----------------
template<int O, int PTS>
__global__ __launch_bounds__(256) void edge_reduce(const float* __restrict__ Y,
    const float* __restrict__ T, const int* __restrict__ idx,
    float* __restrict__ outmax, float* __restrict__ ssum, float* __restrict__ ssq) {
  constexpr int CQ = O / 4;      // channel-quad groups
  constexpr int NG = 256 / CQ;   // point groups per block
  constexpr int PPT = PTS / NG;  // points per thread
  constexpr int BPB = NP / PTS;  // blocks per batch (128)
  __shared__ int sidx[PTS * KK];
  __shared__ float sred[1024], qred[1024];
  const int t = threadIdx.x;
  const int cq = t % CQ, ng = t / CQ;
  const int c = cq * 4;
  const int bid = blockIdx.x;    // 1024 blocks total
  const int g0 = ((bid & 7) * BPB + (bid >> 3)) * PTS;  // XCD-affinity swizzle

  for (int i = t; i < PTS * KK; i += 256) sidx[i] = idx[(size_t)g0 * KK + i];
  __syncthreads();

  float s4[4] = {}, q4[4] = {};
#pragma unroll
  for (int pp = 0; pp < PPT; ++pp) {
    const int p = ng + pp * NG;
    const int g = g0 + p;
    const int base = (g >> 11) * NP;
    const float4 tv = *reinterpret_cast<const float4*>(T + (size_t)g * O + c);
    float4 vs[KK];
#pragma unroll
    for (int k = 0; k < KK; ++k)
      vs[k] = *reinterpret_cast<const float4*>(Y + (size_t)(base + sidx[p * KK + k]) * O + c);
    float m0 = -__builtin_inff(), m1 = m0, m2 = m0, m3 = m0;
#pragma unroll
    for (int k = 0; k < KK; ++k) {
      const float h0 = vs[k].x + tv.x, h1 = vs[k].y + tv.y;
      const float h2 = vs[k].z + tv.z, h3 = vs[k].w + tv.w;
      m0 = fmaxf(m0, h0); m1 = fmaxf(m1, h1); m2 = fmaxf(m2, h2); m3 = fmaxf(m3, h3);
      s4[0] += h0; s4[1] += h1; s4[2] += h2; s4[3] += h3;
      q4[0] = fmaf(h0, h0, q4[0]); q4[1] = fmaf(h1, h1, q4[1]);
      q4[2] = fmaf(h2, h2, q4[2]); q4[3] = fmaf(h3, h3, q4[3]);
    }
    float4 o4; o4.x = m0; o4.y = m1; o4.z = m2; o4.w = m3;
    *reinterpret_cast<float4*>(outmax + (size_t)g * O + c) = o4;
  }

#pragma unroll
  for (int j = 0; j < 4; ++j) { sred[t * 4 + j] = s4[j]; qred[t * 4 + j] = q4[j]; }
  __syncthreads();
  if (t < O) {
    const int cqr = t >> 2, jr = t & 3;
    float s = 0.f, q = 0.f;
#pragma unroll
    for (int n = 0; n < NG; ++n) {
      s += sred[(n * CQ + cqr) * 4 + jr];
      q += qred[(n * CQ + cqr) * 4 + jr];
    }
    atomicAdd(ssum + t, s);
    atomicAdd(ssq + t, q);
  }
}

// ---------------- bn + leaky relu -> fragment-order bf16 planes ----------------
template<int O, bool WN>
__global__ __launch_bounds__(256) void bnrelu_kernel(const float* __restrict__ fA,
    const float* __restrict__ ssum, const float* __restrict__ ssq,
    const float* __restrict__ g, const float* __restrict__ be,
    unsigned short* __restrict__ xh, unsigned short* __restrict__ xl, int colbase,
    float* __restrict__ nrm) {
  constexpr float INV = 1.0f / 327680.0f;  // B*N*K
  constexpr int K8 = O / 8;
  const int id = blockIdx.x * 256 + threadIdx.x;  // 16384*K8 items
  const int r = id & 63;
  const int k8loc = (id >> 6) % K8;
  const int tile = (id >> 6) / K8;
  const int n = tile * 64 + r;
  const int c0 = k8loc * 8;

  float hv[8];
  {
    const float4 p0 = *reinterpret_cast<const float4*>(fA + (size_t)n * O + c0);
    const float4 p1 = *reinterpret_cast<const float4*>(fA + (size_t)n * O + c0 + 4);
    hv[0] = p0.x; hv[1] = p0.y; hv[2] = p0.z; hv[3] = p0.w;
    hv[4] = p1.x; hv[5] = p1.y; hv[6] = p1.z; hv[7] = p1.w;
  }
  unsigned short hh[8], ll[8];
  float s = 0.f;
#pragma unroll
  for (int j = 0; j < 8; ++j) {
    const int col = c0 + j;
    const float m = ssum[col] * INV;
    const float v = ssq[col] * INV - m * m;
    const float sc = g[col] / sqrtf(v + 1e-5f);
    float val = (hv[j] - m) * sc + be[col];
    val = (val >= 0.f) ? val : 0.2f * val;
    split2(val, hh[j], ll[j]);
    const float recon = bff(hh[j]) + bff(ll[j]);
    s = fmaf(recon, recon, s);
  }
  const size_t ob = (((size_t)tile * 64 + (colbase >> 3) + k8loc) * 64 + r) * 8;
  uint4 ph, pl;
  ph.x = (unsigned)hh[0] | ((unsigned)hh[1] << 16);
  ph.y = (unsigned)hh[2] | ((unsigned)hh[3] << 16);
  ph.z = (unsigned)hh[4] | ((unsigned)hh[5] << 16);
  ph.w = (unsigned)hh[6] | ((unsigned)hh[7] << 16);
  pl.x = (unsigned)ll[0] | ((unsigned)ll[1] << 16);
  pl.y = (unsigned)ll[2] | ((unsigned)ll[3] << 16);
  pl.z = (unsigned)ll[4] | ((unsigned)ll[5] << 16);
  pl.w = (unsigned)ll[6] | ((unsigned)ll[7] << 16);
  *reinterpret_cast<uint4*>(xh + ob) = ph;
  *reinterpret_cast<uint4*>(xl + ob) = pl;
  if (WN) atomicAdd(nrm + n, s);
}

// ---------------- final conv + global max pool: single-plane (R12) --------------
__global__ __launch_bounds__(256) void final_mfma(const unsigned short* __restrict__ xh,
    const unsigned short* __restrict__ wfh, unsigned* __restrict__ outenc) {
  __shared__ float fr[128];
  const int t = threadIdx.x, lane = t & 63, w = t >> 6;
  const int half = lane >> 5, l31 = lane & 31;
  const int rt = (w >> 1) * 32, tc = (w & 1) * 32;
  const int b = blockIdx.z, n0 = blockIdx.x * 64, o0 = blockIdx.y * 64;
  const int tn = (b * NP + n0) >> 6, to = o0 >> 6;

  f32x16 acc;
#pragma unroll
  for (int i = 0; i < 16; ++i) acc[i] = 0.f;

  for (int cc = 0; cc < 4; ++cc) {  // 128 channels per chunk
    bf16x8 BH[8];
#pragma unroll
    for (int ch = 0; ch < 8; ++ch) {
      const int k8 = cc * 16 + ch * 2 + half;
      const size_t a = (((size_t)to * 64 + k8) * 64 + tc + l31) * 8;
      BH[ch] = *reinterpret_cast<const bf16x8*>(wfh + a);
    }
#pragma unroll
    for (int ch = 0; ch < 8; ++ch) {
      const int k8 = cc * 16 + ch * 2 + half;
      const size_t a = (((size_t)tn * 64 + k8) * 64 + rt + l31) * 8;
      const bf16x8 ah = *reinterpret_cast<const bf16x8*>(xh + a);
      acc = MF(ah, BH[ch], acc);
    }
  }

  float M = acc[0];
#pragma unroll
  for (int i = 1; i < 16; ++i) M = fmaxf(M, acc[i]);
  M = fmaxf(M, __shfl_xor(M, 32));
  fr[w * 32 + l31] = M;
  __syncthreads();
  if (t < 64) {
    const float Mc = fmaxf(fr[t], fr[64 + t]);
    const unsigned ub = __float_as_uint(Mc);
    const unsigned key = (ub & 0x80000000u) ? ~ub : (ub | 0x80000000u);
    atomicMax(outenc + b * 1024 + o0 + t, key);
  }
}

__global__ __launch_bounds__(256) void decode_kernel(const unsigned int* __restrict__ enc,
    const float* __restrict__ bf, float* __restrict__ out) {
  const int gid = blockIdx.x * 256 + threadIdx.x;  // 8192
  const unsigned key = enc[gid];
  const unsigned ubits = (key & 0x80000000u) ? (key & 0x7fffffffu) : ~key;
  out[gid] = __uint_as_float(ubits) + bf[gid & 1023];
}

// ---------------- launch ----------------
extern "C" void kernel_launch(void* const* d_in, const int* in_sizes, int n_in,
                              void* d_out, int out_size, void* d_ws, size_t ws_size,
                              hipStream_t stream) {
  (void)in_sizes; (void)n_in; (void)out_size; (void)ws_size;
  const float* x   = (const float*)d_in[0];
  const float* W0  = (const float*)d_in[1];
  const float* b0  = (const float*)d_in[2];
  const float* g0  = (const float*)d_in[3];
  const float* be0 = (const float*)d_in[4];
  const float* W1  = (const float*)d_in[5];
  const float* b1  = (const float*)d_in[6];
  const float* g1  = (const float*)d_in[7];
  const float* be1 = (const float*)d_in[8];
  const float* W2  = (const float*)d_in[9];
  const float* b2  = (const float*)d_in[10];
  const float* g2  = (const float*)d_in[11];
  const float* be2 = (const float*)d_in[12];
  const float* W3  = (const float*)d_in[13];
  const float* b3  = (const float*)d_in[14];
  const float* g3  = (const float*)d_in[15];
  const float* be3 = (const float*)d_in[16];
  const float* Wf  = (const float*)d_in[17];
  const float* bf  = (const float*)d_in[18];

  float* wsf = (float*)d_ws;
  int* idxb = (int*)d_ws;                        // 327,680 ints
  float* stats = wsf + 327680;                   // 2048
  float* nb = wsf + 329728;                      // 4 x 16384 norm buffers
  unsigned* outenc = (unsigned*)(wsf + 395264);  // 8192
  float* x4 = wsf + 403456;                      // 65536
  float* featA = wsf + 468992;                   // 16384*256
  float* negd = wsf + 4663296;                   // scratch region (Y/T/cand)
  float* Yb = negd;
  float* Tb = negd + 4194304;
  unsigned long long* cand = (unsigned long long*)(negd + 8388608);  // 5.25 MB
  unsigned short* xh = (unsigned short*)(wsf + 21440512);  // xT hi plane
  unsigned short* xl = xh + 8388608;                       // xT lo plane
  unsigned short* wb1 = xl + 8388608;            // 2*(2*64*64)   = 16384
  unsigned short* wb2 = wb1 + 16384;             // 2*(2*128*64)  = 32768
  unsigned short* wb3 = wb2 + 32768;             // 2*(2*256*128) = 131072
  unsigned short* wfh = wb3 + 131072;            // 1024*512
  unsigned short* wfl = wfh + 524288;

  float* normsA = nb, *normsB = nb + 16384, *normsC = nb + 32768, *normsD = nb + 49152;

  hipMemsetAsync(stats, 0, (2048 + 65536) * sizeof(float), stream);
  hipMemsetAsync(outenc, 0, 8192 * sizeof(unsigned), stream);

  const dim3 blk(256, 1, 1);
  const dim3 fblk(1024, 1, 1);
  const dim3 fgrid(2048, 1, 1);
  const dim3 mgrid(4096, 1, 1);
  const dim3 ergrid(1024, 1, 1);

  pad_norms<<<dim3(64), blk, 0, stream>>>(x, x4, normsA);
  wsplit_all<<<dim3(2224), blk, 0, stream>>>(W1, W2, W3, Wf, wb1, wb2, wb3, wfh, wfl);

  // Layer 0 (C=3 -> 64, out cols [0,64))
  fused_dist_knn0<<<fgrid, fblk, 0, stream>>>(x4, normsA, cand);
  knn_merge<<<mgrid, blk, 0, stream>>>(cand, idxb);
  pt_gemm0<<<dim3(4096), blk, 0, stream>>>(x, W0, b0, Yb, Tb);
  edge_reduce<64, 16><<<ergrid, blk, 0, stream>>>(Yb, Tb, idxb, featA, stats, stats + 256);
  bnrelu_kernel<64, true><<<dim3(512), blk, 0, stream>>>(featA, stats, stats + 256,
      g0, be0, xh, xl, 0, normsB);

  // Layer 1 (64 -> 64, in cols [0,64), out [64,128))
  fused_dist_knn<64><<<fgrid, fblk, 0, stream>>>(xh, xl, 0, normsB, cand);
  knn_merge<<<mgrid, blk, 0, stream>>>(cand, idxb);
  pt_gemm<64, 128><<<dim3(256, 2), blk, 0, stream>>>(xh, xl, 0, wb1, wb1 + 8192, b1, Yb, Tb);
  edge_reduce<64, 16><<<ergrid, blk, 0, stream>>>(Yb, Tb, idxb, featA, stats + 512, stats + 768);
  bnrelu_kernel<64, true><<<dim3(512), blk, 0, stream>>>(featA, stats + 512, stats + 768,
      g1, be1, xh, xl, 64, normsC);

  // Layer 2 (64 -> 128, in cols [64,128), out [128,256))
  fused_dist_knn<64><<<fgrid, fblk, 0, stream>>>(xh, xl, 64, normsC, cand);
  knn_merge<<<mgrid, blk, 0, stream>>>(cand, idxb);
  pt_gemm<64, 256><<<dim3(256, 4), blk, 0, stream>>>(xh, xl, 64, wb2, wb2 + 16384, b2, Yb, Tb);
  edge_reduce<128, 16><<<ergrid, blk, 0, stream>>>(Yb, Tb, idxb, featA, stats + 1024, stats + 1280);
  bnrelu_kernel<128, true><<<dim3(1024), blk, 0, stream>>>(featA, stats + 1024, stats + 1280,
      g2, be2, xh, xl, 128, normsD);

  // Layer 3 (128 -> 256, in cols [128,256), out [256,512))
  fused_dist_knn<128><<<fgrid, fblk, 0, stream>>>(xh, xl, 128, normsD, cand);
  knn_merge<<<mgrid, blk, 0, stream>>>(cand, idxb);
  pt_gemm<128, 512><<<dim3(256, 8), blk, 0, stream>>>(xh, xl, 128, wb3, wb3 + 65536, b3, Yb, Tb);
  edge_reduce<256, 16><<<ergrid, blk, 0, stream>>>(Yb, Tb, idxb, featA, stats + 1536, stats + 1792);
  bnrelu_kernel<256, false><<<dim3(2048), blk, 0, stream>>>(featA, stats + 1536, stats + 1792,
      g3, be3, xh, xl, 256, nullptr);

  // Final 1x1 conv + global max pool (single-plane)
  final_mfma<<<dim3(32, 16, 8), blk, 0, stream>>>(xh, wfh, outenc);
  decode_kernel<<<dim3(32), blk, 0, stream>>>(outenc, bf, (float*)d_out);
}

// Round 15
// 487.529 us; speedup vs baseline: 1.0821x; 1.0821x over previous
//
#include <hip/hip_runtime.h>
#include <cstdint>
#include <cstddef>

// DGCNN forward. R26: R23 (passing best) + rotation-swizzle b128 scan.
// R25 failed correctness: 11-bit key truncation (lane-in-key) merged distances
// at 2.4e-4 relative -> neighbor flips compounded past threshold. Lesson: knn
// tolerates ~1e-4 distance perturbation; R23's 5-bit pos truncation is safe
// (passed twice). R26 restores R23's key format / ballot winner / tie-break
// EXACTLY and changes only the LDS physical layout: rotation swizzle
// phys(c) = (c&~31)|((c+4*((c>>5)&7))&31) is 16B-aligned, so the select's
// initial scan becomes 8x ds_read_b128 instead of 32x ds_read_b32 (keys carry
// their position, so scan order is irrelevant). Refill broadcast (banks
// (i31+rot)&31 distinct) and lane-0 poke stay conflict-free.

constexpr int NB = 8;
constexpr int NP = 2048;
constexpr int KK = 20;

typedef short bf16x8 __attribute__((ext_vector_type(8)));
typedef float f32x16 __attribute__((ext_vector_type(16)));
typedef float f32x4 __attribute__((ext_vector_type(4)));

__device__ __forceinline__ f32x16 MF(bf16x8 a, bf16x8 b, f32x16 c) {
  return __builtin_amdgcn_mfma_f32_32x32x16_bf16(a, b, c, 0, 0, 0);
}
__device__ __forceinline__ f32x4 MF16(bf16x8 a, bf16x8 b, f32x4 c) {
  return __builtin_amdgcn_mfma_f32_16x16x32_bf16(a, b, c, 0, 0, 0);
}
__device__ __forceinline__ unsigned short bfh(float f) {
  return (unsigned short)(__float_as_uint(f) >> 16);  // truncating bf16
}
__device__ __forceinline__ float bff(unsigned short u) {
  return __uint_as_float(((unsigned)u) << 16);
}
__device__ __forceinline__ void split2(float v, unsigned short& h, unsigned short& l) {
  h = bfh(v); l = bfh(v - bff(h));
}
// rotation swizzle: rotate within each 32-col segment by 4*(owner&7) words.
// 16B-aligned (rotation multiple of 4) -> b128 scan reads.
__device__ __forceinline__ int PHYS(int c) {
  return (c & ~31) | ((c + 4 * ((c >> 5) & 7)) & 31);
}
// monotone key: flip float bits, embed (31 - in-lane pos) in low 5 bits.
// (R23 format -- passed twice.)
__device__ __forceinline__ unsigned packkey(float d, int col) {
  const unsigned u = __float_as_uint(d);
  const unsigned k = (u & 0x80000000u) ? ~u : (u | 0x80000000u);
  return (k & ~31u) | (31u - ((unsigned)col & 31u));
}

// full-wave unsigned max via DPP (identity 0); uniform result in all lanes.
__device__ __forceinline__ unsigned wavemaxu(unsigned v) {
  int x = (int)v, t;
  t = __builtin_amdgcn_update_dpp(0, x, 0x111, 0xf, 0xf, false);  // row_shr:1
  x = (int)(((unsigned)x > (unsigned)t) ? (unsigned)x : (unsigned)t);
  t = __builtin_amdgcn_update_dpp(0, x, 0x112, 0xf, 0xf, false);  // row_shr:2
  x = (int)(((unsigned)x > (unsigned)t) ? (unsigned)x : (unsigned)t);
  t = __builtin_amdgcn_update_dpp(0, x, 0x114, 0xf, 0xf, false);  // row_shr:4
  x = (int)(((unsigned)x > (unsigned)t) ? (unsigned)x : (unsigned)t);
  t = __builtin_amdgcn_update_dpp(0, x, 0x118, 0xf, 0xf, false);  // row_shr:8
  x = (int)(((unsigned)x > (unsigned)t) ? (unsigned)x : (unsigned)t);
  t = __builtin_amdgcn_update_dpp(0, x, 0x142, 0xf, 0xf, false);  // row_bcast15
  x = (int)(((unsigned)x > (unsigned)t) ? (unsigned)x : (unsigned)t);
  t = __builtin_amdgcn_update_dpp(0, x, 0x143, 0xf, 0xf, false);  // row_bcast31
  x = (int)(((unsigned)x > (unsigned)t) ? (unsigned)x : (unsigned)t);
  return (unsigned)__builtin_amdgcn_readlane(x, 63);
}

// ---------------- pad x -> x4, plus L0 norms ----------------
__global__ __launch_bounds__(256) void pad_norms(const float* __restrict__ x,
    float* __restrict__ x4, float* __restrict__ nrm) {
  const int p = blockIdx.x * 256 + threadIdx.x;  // 16384
  float4 v;
  v.x = x[p * 3 + 0]; v.y = x[p * 3 + 1]; v.z = x[p * 3 + 2]; v.w = 0.f;
  *reinterpret_cast<float4*>(x4 + (size_t)p * 4) = v;
  nrm[p] = v.x * v.x + v.y * v.y + v.z * v.z;
}

// ---------------- all weight splits, fragment-order output ----------------
__global__ __launch_bounds__(256) void wsplit_all(const float* __restrict__ W1,
    const float* __restrict__ W2, const float* __restrict__ W3,
    const float* __restrict__ Wf,
    unsigned short* __restrict__ wb1, unsigned short* __restrict__ wb2,
    unsigned short* __restrict__ wb3,
    unsigned short* __restrict__ wfh, unsigned short* __restrict__ wfl) {
  const int id = blockIdx.x * 256 + threadIdx.x;  // 569344 total
  if (id < 524288) {
    const int row = id >> 9, c = id & 511;
    unsigned short h, l;
    split2(Wf[id], h, l);
    const size_t a = ((((size_t)(row >> 6)) * 64 + (c >> 3)) * 64 + (row & 63)) * 8 + (c & 7);
    wfh[a] = h; wfl[a] = l;
    return;
  }
  int id2 = id - 524288;
  const float* W; unsigned short* wb; int O, C;
  if (id2 < 4096)      { W = W1; wb = wb1; O = 64;  C = 64;  }
  else if (id2 < 12288){ W = W2; wb = wb2; O = 128; C = 64;  id2 -= 4096; }
  else                 { W = W3; wb = wb3; O = 256; C = 128; id2 -= 12288; }
  const int o = id2 / C, c = id2 % C;
  const int K8 = C >> 3;
  const float w1 = W[o * 2 * C + c];
  const float w2 = W[o * 2 * C + C + c];
  unsigned short h, l;
  const int r1 = o, rd = O + o;
  const size_t a1 = (((size_t)(r1 >> 6) * K8 + (c >> 3)) * 64 + (r1 & 63)) * 8 + (c & 7);
  const size_t ad = (((size_t)(rd >> 6) * K8 + (c >> 3)) * 64 + (rd & 63)) * 8 + (c & 7);
  split2(w1, h, l);
  wb[a1] = h; wb[2 * O * C + a1] = l;
  split2(w2 - w1, h, l);
  wb[ad] = h; wb[2 * O * C + ad] = l;
}

// ---------------- top-20 select on packed keys (R23 semantics) ------------------
// Lane owns cols [lane*32, lane*32+32); rotation-swizzled phys layout. Keys
// carry 5-bit pos -> b128 scan order-independent. Winner lane via ballot
// (lowest lane on ties = lowest col); winner pos from wm's low bits. Lane-0
// poke (uniform addr); fenced cooperative refill on exhaustion.
__device__ __forceinline__ void select20(unsigned* __restrict__ srow,
    const int lane, int* __restrict__ op) {
  const int i31 = lane & 31;
  const int rot = 4 * (lane & 7);
  unsigned k1 = 0u, k2 = 0u;
#pragma unroll
  for (int q = 0; q < 8; ++q) {
    const uint4 v4 = *reinterpret_cast<const uint4*>(srow + lane * 32 + ((4 * q + rot) & 31));
    {
      const unsigned e = v4.x, lo = (k1 < e) ? k1 : e;
      k1 = (k1 > e) ? k1 : e; k2 = (k2 > lo) ? k2 : lo;
    }
    {
      const unsigned e = v4.y, lo = (k1 < e) ? k1 : e;
      k1 = (k1 > e) ? k1 : e; k2 = (k2 > lo) ? k2 : lo;
    }
    {
      const unsigned e = v4.z, lo = (k1 < e) ? k1 : e;
      k1 = (k1 > e) ? k1 : e; k2 = (k2 > lo) ? k2 : lo;
    }
    {
      const unsigned e = v4.w, lo = (k1 < e) ? k1 : e;
      k1 = (k1 > e) ? k1 : e; k2 = (k2 > lo) ? k2 : lo;
    }
  }
  int mycol = 0;
#pragma unroll
  for (int r = 0; r < KK; ++r) {
    const unsigned wm = wavemaxu(k1);
    const unsigned long long bal = __ballot(k1 == wm);
    const int wl = bal ? (__ffsll(bal) - 1) : 0;
    const int mwin = 31 - (int)(wm & 31u);
    const int col = wl * 32 + mwin;
    if (lane == r) mycol = col;
    if (lane == 0) srow[wl * 32 + ((mwin + 4 * (wl & 7)) & 31)] = 0u;  // poke
    if (lane == wl) { k1 = k2; k2 = 0u; }
    // only a twice-popped winner can have k1==0 (real keys are never 0)
    if (__ballot(k1 == 0u)) {
      asm volatile("s_waitcnt lgkmcnt(0)" ::: "memory");  // drain pokes
      __builtin_amdgcn_sched_barrier(0);                  // rule #18 fence
      const unsigned e = srow[wl * 32 + ((i31 + 4 * (wl & 7)) & 31)];
      const unsigned nm = wavemaxu(e);                    // poked slots = 0
      if (lane == wl) k1 = nm;
    }
  }
  if (lane < KK) op[lane] = mycol;  // coalesced 20-lane store
}

// ---------------- fused dist+knn, L0 (C=3, fp32) ----------------
__global__ __launch_bounds__(1024) void fused_dist_knn0(const float* __restrict__ X4,
    const float* __restrict__ norms, int* __restrict__ idxout) {
  __shared__ unsigned sdist[16][2048];
  const int t = threadIdx.x, lane = t & 63, w = t >> 6;  // w: 0..15
  const int l15 = lane & 15, g4 = lane >> 4;
  const int bid = blockIdx.x;          // 1024
  const int b = bid & 7, g = bid >> 3; // XCD-batch affinity
  const int i0 = g * 16;

  float4 rx[4]; float ni[4];
#pragma unroll
  for (int e = 0; e < 4; ++e) {
    const int p = b * NP + i0 + g4 * 4 + e;
    rx[e] = *reinterpret_cast<const float4*>(X4 + (size_t)p * 4);
    ni[e] = norms[p];
  }

  for (int it = 0; it < 8; ++it) {
    const int jl = it * 256 + w * 16 + l15;
    const int p = b * NP + jl;
    const float4 cj = *reinterpret_cast<const float4*>(X4 + (size_t)p * 4);
    const float nj = norms[p];
    const int ps = PHYS(jl);
#pragma unroll
    for (int e = 0; e < 4; ++e) {
      float acc = fmaf(rx[e].x, cj.x, 0.f);
      acc = fmaf(rx[e].y, cj.y, acc);
      acc = fmaf(rx[e].z, cj.z, acc);
      sdist[g4 * 4 + e][ps] = packkey(2.f * acc - ni[e] - nj, jl);
    }
  }
  __syncthreads();

  select20(&sdist[w][0], lane, idxout + (size_t)(b * NP + i0 + w) * KK);
}

// ---------------- fused dist+knn (l>=1): MFMA 16x16x32, swizzled LDS ------------
template<int C>
__global__ __launch_bounds__(1024) void fused_dist_knn(const unsigned short* __restrict__ xh,
    const unsigned short* __restrict__ xl, int colbase,
    const float* __restrict__ norms, int* __restrict__ idxout) {
  constexpr int KB = C / 32;  // K-blocks per chain
  __shared__ unsigned sdist[16][2048];
  const int t = threadIdx.x, lane = t & 63, w = t >> 6;  // w: 0..15
  const int l15 = lane & 15, g4 = lane >> 4;
  const int bid = blockIdx.x;          // 1024
  const int b = bid & 7, g = bid >> 3; // XCD-batch affinity
  const int i0 = g * 16;
  const int ti = (b * NP + i0) >> 6;
  const int ir = i0 & 63;
  const int k8b = colbase >> 3;

  bf16x8 AH[KB], AL[KB];
#pragma unroll
  for (int kb = 0; kb < KB; ++kb) {
    const size_t a = (((size_t)ti * 64 + k8b + kb * 4 + g4) * 64 + ir + l15) * 8;
    AH[kb] = *reinterpret_cast<const bf16x8*>(xh + a);
    AL[kb] = *reinterpret_cast<const bf16x8*>(xl + a);
  }
  float ni[4];
#pragma unroll
  for (int e = 0; e < 4; ++e) ni[e] = norms[b * NP + i0 + g4 * 4 + e];

  for (int it = 0; it < 8; ++it) {
    const int j0 = it * 256 + w * 16;
    const int tj = (b * NP + j0) >> 6;
    const int jr = j0 & 63;
    bf16x8 BH[KB], BL[KB];
#pragma unroll
    for (int kb = 0; kb < KB; ++kb) {
      const size_t a = (((size_t)tj * 64 + k8b + kb * 4 + g4) * 64 + jr + l15) * 8;
      BH[kb] = *reinterpret_cast<const bf16x8*>(xh + a);
      BL[kb] = *reinterpret_cast<const bf16x8*>(xl + a);
    }
    f32x4 acc = {0.f, 0.f, 0.f, 0.f};
#pragma unroll
    for (int kb = 0; kb < KB; ++kb) {
      acc = MF16(AH[kb], BH[kb], acc);
      acc = MF16(AH[kb], BL[kb], acc);
      acc = MF16(AL[kb], BH[kb], acc);
    }
    const float nj = norms[b * NP + j0 + l15];
    const int ps = PHYS(j0 + l15);
#pragma unroll
    for (int e = 0; e < 4; ++e)
      sdist[g4 * 4 + e][ps] = packkey(2.f * acc[e] - ni[e] - nj, j0 + l15);
  }
  __syncthreads();

  select20(&sdist[w][0], lane, idxout + (size_t)(b * NP + i0 + w) * KK);
}

// ---------------- per-point GEMM, L0 (C=3, fp32 vector) ----------------
__global__ __launch_bounds__(256) void pt_gemm0(const float* __restrict__ x,
    const float* __restrict__ W, const float* __restrict__ bias,
    float* __restrict__ Y, float* __restrict__ T) {
  const int t = threadIdx.x;
  const int o = t & 63;
  const int g = blockIdx.x * 4 + (t >> 6);  // 0..16383
  const float x0 = x[(size_t)g * 3 + 0], x1 = x[(size_t)g * 3 + 1], x2 = x[(size_t)g * 3 + 2];
  const float w10 = W[o * 6 + 0], w11 = W[o * 6 + 1], w12 = W[o * 6 + 2];
  const float w20 = W[o * 6 + 3], w21 = W[o * 6 + 4], w22 = W[o * 6 + 5];
  Y[(size_t)g * 64 + o] = w10 * x0 + w11 * x1 + w12 * x2;
  T[(size_t)g * 64 + o] = (w20 - w10) * x0 + (w21 - w11) * x1 + (w22 - w12) * x2 + bias[o];
}

// ---------------- per-point GEMM (l>=1): LDS-free, [Y||T] = X Wcat^T ----------------
template<int C, int O2>  // O2 = 2*O
__global__ __launch_bounds__(256) void pt_gemm(const unsigned short* __restrict__ xh,
    const unsigned short* __restrict__ xl, int colbase,
    const unsigned short* __restrict__ wch, const unsigned short* __restrict__ wcl,
    const float* __restrict__ bias, float* __restrict__ Y, float* __restrict__ T) {
  constexpr int K8 = C / 8;
  constexpr int H = K8 / 2;
  constexpr int O = O2 / 2;
  const int t = threadIdx.x, lane = t & 63, w = t >> 6;
  const int half = lane >> 5, l31 = lane & 31;
  const int rt = (w >> 1) * 32, tc = (w & 1) * 32;
  const int n0 = blockIdx.x * 64, o0 = blockIdx.y * 64;
  const int tn = n0 >> 6, to = o0 >> 6;
  const int k8b = colbase >> 3;
  const int col = o0 + tc + l31;

  bf16x8 BH[H], BL[H];
#pragma unroll
  for (int ch = 0; ch < H; ++ch) {
    const size_t a = (((size_t)to * K8 + ch * 2 + half) * 64 + tc + l31) * 8;
    BH[ch] = *reinterpret_cast<const bf16x8*>(wch + a);
    BL[ch] = *reinterpret_cast<const bf16x8*>(wcl + a);
  }

  f32x16 acc;
#pragma unroll
  for (int i = 0; i < 16; ++i) acc[i] = 0.f;
#pragma unroll
  for (int ch = 0; ch < H; ++ch) {
    const size_t a = (((size_t)tn * 64 + k8b + ch * 2 + half) * 64 + rt + l31) * 8;
    const bf16x8 ah = *reinterpret_cast<const bf16x8*>(xh + a);
    const bf16x8 al = *reinterpret_cast<const bf16x8*>(xl + a);
    acc = MF(ah, BH[ch], acc); acc = MF(ah, BL[ch], acc); acc = MF(al, BH[ch], acc);
  }

  if (col < O) {
#pragma unroll
    for (int i = 0; i < 16; ++i) {
      const int row = n0 + rt + (i & 3) + 8 * (i >> 2) + 4 * half;
      Y[(size_t)row * O + col] = acc[i];
    }
  } else {
    const float bv = bias[col - O];
#pragma unroll
    for (int i = 0; i < 16; ++i) {
      const int row = n0 + rt + (i & 3) + 8 * (i >> 2) + 4 * half;
      T[(size_t)row * O + (col - O)] = acc[i] + bv;
    }
  }
}

// ---------------- edge reduce: max/sum/sumsq over gathered Y rows ----------------
template<int O, int PTS>
__global__ __launch_bounds__(256) void edge_reduce(const float* __restrict__ Y,
    const float* __restrict__ T, const int* __restrict__ idx,
    float* __restrict__ outmax, float* __restrict__ ssum, float* __restrict__ ssq) {
  constexpr int CQ = O / 4;      // channel-quad groups
  constexpr int NG = 256 / CQ;   // point groups per block
  constexpr int PPT = PTS / NG;  // points per thread
  constexpr int BPB = NP / PTS;  // blocks per batch (128)
  __shared__ int sidx[PTS * KK];
  __shared__ float sred[1024], qred[1024];
  const int t = threadIdx.x;
  const int cq = t % CQ, ng = t / CQ;
  const int c = cq * 4;
  const int bid = blockIdx.x;    // 1024 blocks total
  const int g0 = ((bid & 7) * BPB + (bid >> 3)) * PTS;  // XCD-affinity swizzle

  for (int i = t; i < PTS * KK; i += 256) sidx[i] = idx[(size_t)g0 * KK + i];
  __syncthreads();

  float s4[4] = {}, q4[4] = {};
#pragma unroll
  for (int pp = 0; pp < PPT; ++pp) {
    const int p = ng + pp * NG;
    const int g = g0 + p;
    const int base = (g >> 11) * NP;
    const float4 tv = *reinterpret_cast<const float4*>(T + (size_t)g * O + c);
    float4 vs[KK];
#pragma unroll
    for (int k = 0; k < KK; ++k)
      vs[k] = *reinterpret_cast<const float4*>(Y + (size_t)(base + sidx[p * KK + k]) * O + c);
    float m0 = -__builtin_inff(), m1 = m0, m2 = m0, m3 = m0;
#pragma unroll
    for (int k = 0; k < KK; ++k) {
      const float h0 = vs[k].x + tv.x, h1 = vs[k].y + tv.y;
      const float h2 = vs[k].z + tv.z, h3 = vs[k].w + tv.w;
      m0 = fmaxf(m0, h0); m1 = fmaxf(m1, h1); m2 = fmaxf(m2, h2); m3 = fmaxf(m3, h3);
      s4[0] += h0; s4[1] += h1; s4[2] += h2; s4[3] += h3;
      q4[0] = fmaf(h0, h0, q4[0]); q4[1] = fmaf(h1, h1, q4[1]);
      q4[2] = fmaf(h2, h2, q4[2]); q4[3] = fmaf(h3, h3, q4[3]);
    }
    float4 o4; o4.x = m0; o4.y = m1; o4.z = m2; o4.w = m3;
    *reinterpret_cast<float4*>(outmax + (size_t)g * O + c) = o4;
  }

#pragma unroll
  for (int j = 0; j < 4; ++j) { sred[t * 4 + j] = s4[j]; qred[t * 4 + j] = q4[j]; }
  __syncthreads();
  if (t < O) {
    const int cqr = t >> 2, jr = t & 3;
    float s = 0.f, q = 0.f;
#pragma unroll
    for (int n = 0; n < NG; ++n) {
      s += sred[(n * CQ + cqr) * 4 + jr];
      q += qred[(n * CQ + cqr) * 4 + jr];
    }
    atomicAdd(ssum + t, s);
    atomicAdd(ssq + t, q);
  }
}

// ---------------- bn + leaky relu -> fragment-order bf16 planes ----------------
template<int O, bool WN>
__global__ __launch_bounds__(256) void bnrelu_kernel(const float* __restrict__ fA,
    const float* __restrict__ ssum, const float* __restrict__ ssq,
    const float* __restrict__ g, const float* __restrict__ be,
    unsigned short* __restrict__ xh, unsigned short* __restrict__ xl, int colbase,
    float* __restrict__ nrm) {
  constexpr float INV = 1.0f / 327680.0f;  // B*N*K
  constexpr int K8 = O / 8;
  const int id = blockIdx.x * 256 + threadIdx.x;  // 16384*K8 items
  const int r = id & 63;
  const int k8loc = (id >> 6) % K8;
  const int tile = (id >> 6) / K8;
  const int n = tile * 64 + r;
  const int c0 = k8loc * 8;

  float hv[8];
  {
    const float4 p0 = *reinterpret_cast<const float4*>(fA + (size_t)n * O + c0);
    const float4 p1 = *reinterpret_cast<const float4*>(fA + (size_t)n * O + c0 + 4);
    hv[0] = p0.x; hv[1] = p0.y; hv[2] = p0.z; hv[3] = p0.w;
    hv[4] = p1.x; hv[5] = p1.y; hv[6] = p1.z; hv[7] = p1.w;
  }
  unsigned short hh[8], ll[8];
  float s = 0.f;
#pragma unroll
  for (int j = 0; j < 8; ++j) {
    const int col = c0 + j;
    const float m = ssum[col] * INV;
    const float v = ssq[col] * INV - m * m;
    const float sc = g[col] / sqrtf(v + 1e-5f);
    float val = (hv[j] - m) * sc + be[col];
    val = (val >= 0.f) ? val : 0.2f * val;
    split2(val, hh[j], ll[j]);
    const float recon = bff(hh[j]) + bff(ll[j]);
    s = fmaf(recon, recon, s);
  }
  const size_t ob = (((size_t)tile * 64 + (colbase >> 3) + k8loc) * 64 + r) * 8;
  uint4 ph, pl;
  ph.x = (unsigned)hh[0] | ((unsigned)hh[1] << 16);
  ph.y = (unsigned)hh[2] | ((unsigned)hh[3] << 16);
  ph.z = (unsigned)hh[4] | ((unsigned)hh[5] << 16);
  ph.w = (unsigned)hh[6] | ((unsigned)hh[7] << 16);
  pl.x = (unsigned)ll[0] | ((unsigned)ll[1] << 16);
  pl.y = (unsigned)ll[2] | ((unsigned)ll[3] << 16);
  pl.z = (unsigned)ll[4] | ((unsigned)ll[5] << 16);
  pl.w = (unsigned)ll[6] | ((unsigned)ll[7] << 16);
  *reinterpret_cast<uint4*>(xh + ob) = ph;
  *reinterpret_cast<uint4*>(xl + ob) = pl;
  if (WN) atomicAdd(nrm + n, s);
}

// ---------------- final conv + global max pool: single-plane (R12) --------------
__global__ __launch_bounds__(256) void final_mfma(const unsigned short* __restrict__ xh,
    const unsigned short* __restrict__ wfh, unsigned* __restrict__ outenc) {
  __shared__ float fr[128];
  const int t = threadIdx.x, lane = t & 63, w = t >> 6;
  const int half = lane >> 5, l31 = lane & 31;
  const int rt = (w >> 1) * 32, tc = (w & 1) * 32;
  const int b = blockIdx.z, n0 = blockIdx.x * 64, o0 = blockIdx.y * 64;
  const int tn = (b * NP + n0) >> 6, to = o0 >> 6;

  f32x16 acc;
#pragma unroll
  for (int i = 0; i < 16; ++i) acc[i] = 0.f;

  for (int cc = 0; cc < 4; ++cc) {  // 128 channels per chunk
    bf16x8 BH[8];
#pragma unroll
    for (int ch = 0; ch < 8; ++ch) {
      const int k8 = cc * 16 + ch * 2 + half;
      const size_t a = (((size_t)to * 64 + k8) * 64 + tc + l31) * 8;
      BH[ch] = *reinterpret_cast<const bf16x8*>(wfh + a);
    }
#pragma unroll
    for (int ch = 0; ch < 8; ++ch) {
      const int k8 = cc * 16 + ch * 2 + half;
      const size_t a = (((size_t)tn * 64 + k8) * 64 + rt + l31) * 8;
      const bf16x8 ah = *reinterpret_cast<const bf16x8*>(xh + a);
      acc = MF(ah, BH[ch], acc);
    }
  }

  float M = acc[0];
#pragma unroll
  for (int i = 1; i < 16; ++i) M = fmaxf(M, acc[i]);
  M = fmaxf(M, __shfl_xor(M, 32));
  fr[w * 32 + l31] = M;
  __syncthreads();
  if (t < 64) {
    const float Mc = fmaxf(fr[t], fr[64 + t]);
    const unsigned ub = __float_as_uint(Mc);
    const unsigned key = (ub & 0x80000000u) ? ~ub : (ub | 0x80000000u);
    atomicMax(outenc + b * 1024 + o0 + t, key);
  }
}

__global__ __launch_bounds__(256) void decode_kernel(const unsigned int* __restrict__ enc,
    const float* __restrict__ bf, float* __restrict__ out) {
  const int gid = blockIdx.x * 256 + threadIdx.x;  // 8192
  const unsigned key = enc[gid];
  const unsigned ubits = (key & 0x80000000u) ? (key & 0x7fffffffu) : ~key;
  out[gid] = __uint_as_float(ubits) + bf[gid & 1023];
}

// ---------------- launch ----------------
extern "C" void kernel_launch(void* const* d_in, const int* in_sizes, int n_in,
                              void* d_out, int out_size, void* d_ws, size_t ws_size,
                              hipStream_t stream) {
  (void)in_sizes; (void)n_in; (void)out_size; (void)ws_size;
  const float* x   = (const float*)d_in[0];
  const float* W0  = (const float*)d_in[1];
  const float* b0  = (const float*)d_in[2];
  const float* g0  = (const float*)d_in[3];
  const float* be0 = (const float*)d_in[4];
  const float* W1  = (const float*)d_in[5];
  const float* b1  = (const float*)d_in[6];
  const float* g1  = (const float*)d_in[7];
  const float* be1 = (const float*)d_in[8];
  const float* W2  = (const float*)d_in[9];
  const float* b2  = (const float*)d_in[10];
  const float* g2  = (const float*)d_in[11];
  const float* be2 = (const float*)d_in[12];
  const float* W3  = (const float*)d_in[13];
  const float* b3  = (const float*)d_in[14];
  const float* g3  = (const float*)d_in[15];
  const float* be3 = (const float*)d_in[16];
  const float* Wf  = (const float*)d_in[17];
  const float* bf  = (const float*)d_in[18];

  float* wsf = (float*)d_ws;
  int* idxb = (int*)d_ws;                        // 327,680 ints
  float* stats = wsf + 327680;                   // 2048
  float* nb = wsf + 329728;                      // 4 x 16384 norm buffers
  unsigned* outenc = (unsigned*)(wsf + 395264);  // 8192
  float* x4 = wsf + 403456;                      // 65536
  float* featA = wsf + 468992;                   // 16384*256
  float* negd = wsf + 4663296;                   // scratch region (Y/T)
  float* Yb = negd;
  float* Tb = negd + 4194304;
  unsigned short* xh = (unsigned short*)(wsf + 21440512);  // xT hi plane
  unsigned short* xl = xh + 8388608;                       // xT lo plane
  unsigned short* wb1 = xl + 8388608;            // 2*(2*64*64)   = 16384
  unsigned short* wb2 = wb1 + 16384;             // 2*(2*128*64)  = 32768
  unsigned short* wb3 = wb2 + 32768;             // 2*(2*256*128) = 131072
  unsigned short* wfh = wb3 + 131072;            // 1024*512
  unsigned short* wfl = wfh + 524288;

  float* normsA = nb, *normsB = nb + 16384, *normsC = nb + 32768, *normsD = nb + 49152;

  hipMemsetAsync(stats, 0, (2048 + 65536) * sizeof(float), stream);
  hipMemsetAsync(outenc, 0, 8192 * sizeof(unsigned), stream);

  const dim3 blk(256, 1, 1);
  const dim3 fblk(1024, 1, 1);
  const dim3 fgrid(1024, 1, 1);
  const dim3 ergrid(1024, 1, 1);

  pad_norms<<<dim3(64), blk, 0, stream>>>(x, x4, normsA);
  wsplit_all<<<dim3(2224), blk, 0, stream>>>(W1, W2, W3, Wf, wb1, wb2, wb3, wfh, wfl);

  // Layer 0 (C=3 -> 64, out cols [0,64))
  fused_dist_knn0<<<fgrid, fblk, 0, stream>>>(x4, normsA, idxb);
  pt_gemm0<<<dim3(4096), blk, 0, stream>>>(x, W0, b0, Yb, Tb);
  edge_reduce<64, 16><<<ergrid, blk, 0, stream>>>(Yb, Tb, idxb, featA, stats, stats + 256);
  bnrelu_kernel<64, true><<<dim3(512), blk, 0, stream>>>(featA, stats, stats + 256,
      g0, be0, xh, xl, 0, normsB);

  // Layer 1 (64 -> 64, in cols [0,64), out [64,128))
  fused_dist_knn<64><<<fgrid, fblk, 0, stream>>>(xh, xl, 0, normsB, idxb);
  pt_gemm<64, 128><<<dim3(256, 2), blk, 0, stream>>>(xh, xl, 0, wb1, wb1 + 8192, b1, Yb, Tb);
  edge_reduce<64, 16><<<ergrid, blk, 0, stream>>>(Yb, Tb, idxb, featA, stats + 512, stats + 768);
  bnrelu_kernel<64, true><<<dim3(512), blk, 0, stream>>>(featA, stats + 512, stats + 768,
      g1, be1, xh, xl, 64, normsC);

  // Layer 2 (64 -> 128, in cols [64,128), out [128,256))
  fused_dist_knn<64><<<fgrid, fblk, 0, stream>>>(xh, xl, 64, normsC, idxb);
  pt_gemm<64, 256><<<dim3(256, 4), blk, 0, stream>>>(xh, xl, 64, wb2, wb2 + 16384, b2, Yb, Tb);
  edge_reduce<128, 16><<<ergrid, blk, 0, stream>>>(Yb, Tb, idxb, featA, stats + 1024, stats + 1280);
  bnrelu_kernel<128, true><<<dim3(1024), blk, 0, stream>>>(featA, stats + 1024, stats + 1280,
      g2, be2, xh, xl, 128, normsD);

  // Layer 3 (128 -> 256, in cols [128,256), out [256,512))
  fused_dist_knn<128><<<fgrid, fblk, 0, stream>>>(xh, xl, 128, normsD, idxb);
  pt_gemm<128, 512><<<dim3(256, 8), blk, 0, stream>>>(xh, xl, 128, wb3, wb3 + 65536, b3, Yb, Tb);
  edge_reduce<256, 16><<<ergrid, blk, 0, stream>>>(Yb, Tb, idxb, featA, stats + 1536, stats + 1792);
  bnrelu_kernel<256, false><<<dim3(2048), blk, 0, stream>>>(featA, stats + 1536, stats + 1792,
      g3, be3, xh, xl, 256, nullptr);

  // Final 1x1 conv + global max pool (single-plane)
  final_mfma<<<dim3(32, 16, 8), blk, 0, stream>>>(xh, wfh, outenc);
  decode_kernel<<<dim3(32), blk, 0, stream>>>(outenc, bf, (float*)d_out);
}

// Round 16
// 477.790 us; speedup vs baseline: 1.1042x; 1.0204x over previous
//
#include <hip/hip_runtime.h>
#include <cstdint>
#include <cstddef>

// DGCNN forward. R27: 2-tile final_mfma / pt_gemm (B-frag reuse, 2x MLP).
// R26 = session best (487.5us); fused_dist_knn (4x67us) is locally converged:
// 128KB fp32-precision keys are irreducible (R25: key truncation <1e-4 breaks
// knn), so 1 block/CU + two-phase structure stands (R22/R24 64KB geometries
// both lost by duplicating MFMA or rounds). R27 attacks the next tier:
// final_mfma and pt_gemm are L2-latency-bound with VGPR=44 (too few loads in
// flight, R11 diagnosis). Each block now computes TWO n-tiles reusing the B
// fragments: half the B traffic, 2x independent loads+MFMAs in flight.
// Arithmetic bit-identical per element (max-pool order-independent).

constexpr int NB = 8;
constexpr int NP = 2048;
constexpr int KK = 20;

typedef short bf16x8 __attribute__((ext_vector_type(8)));
typedef float f32x16 __attribute__((ext_vector_type(16)));
typedef float f32x4 __attribute__((ext_vector_type(4)));

__device__ __forceinline__ f32x16 MF(bf16x8 a, bf16x8 b, f32x16 c) {
  return __builtin_amdgcn_mfma_f32_32x32x16_bf16(a, b, c, 0, 0, 0);
}
__device__ __forceinline__ f32x4 MF16(bf16x8 a, bf16x8 b, f32x4 c) {
  return __builtin_amdgcn_mfma_f32_16x16x32_bf16(a, b, c, 0, 0, 0);
}
__device__ __forceinline__ unsigned short bfh(float f) {
  return (unsigned short)(__float_as_uint(f) >> 16);  // truncating bf16
}
__device__ __forceinline__ float bff(unsigned short u) {
  return __uint_as_float(((unsigned)u) << 16);
}
__device__ __forceinline__ void split2(float v, unsigned short& h, unsigned short& l) {
  h = bfh(v); l = bfh(v - bff(h));
}
// rotation swizzle: rotate within each 32-col segment by 4*(owner&7) words.
// 16B-aligned (rotation multiple of 4) -> b128 scan reads.
__device__ __forceinline__ int PHYS(int c) {
  return (c & ~31) | ((c + 4 * ((c >> 5) & 7)) & 31);
}
// monotone key: flip float bits, embed (31 - in-lane pos) in low 5 bits.
__device__ __forceinline__ unsigned packkey(float d, int col) {
  const unsigned u = __float_as_uint(d);
  const unsigned k = (u & 0x80000000u) ? ~u : (u | 0x80000000u);
  return (k & ~31u) | (31u - ((unsigned)col & 31u));
}

// full-wave unsigned max via DPP (identity 0); uniform result in all lanes.
__device__ __forceinline__ unsigned wavemaxu(unsigned v) {
  int x = (int)v, t;
  t = __builtin_amdgcn_update_dpp(0, x, 0x111, 0xf, 0xf, false);  // row_shr:1
  x = (int)(((unsigned)x > (unsigned)t) ? (unsigned)x : (unsigned)t);
  t = __builtin_amdgcn_update_dpp(0, x, 0x112, 0xf, 0xf, false);  // row_shr:2
  x = (int)(((unsigned)x > (unsigned)t) ? (unsigned)x : (unsigned)t);
  t = __builtin_amdgcn_update_dpp(0, x, 0x114, 0xf, 0xf, false);  // row_shr:4
  x = (int)(((unsigned)x > (unsigned)t) ? (unsigned)x : (unsigned)t);
  t = __builtin_amdgcn_update_dpp(0, x, 0x118, 0xf, 0xf, false);  // row_shr:8
  x = (int)(((unsigned)x > (unsigned)t) ? (unsigned)x : (unsigned)t);
  t = __builtin_amdgcn_update_dpp(0, x, 0x142, 0xf, 0xf, false);  // row_bcast15
  x = (int)(((unsigned)x > (unsigned)t) ? (unsigned)x : (unsigned)t);
  t = __builtin_amdgcn_update_dpp(0, x, 0x143, 0xf, 0xf, false);  // row_bcast31
  x = (int)(((unsigned)x > (unsigned)t) ? (unsigned)x : (unsigned)t);
  return (unsigned)__builtin_amdgcn_readlane(x, 63);
}

// ---------------- pad x -> x4, plus L0 norms ----------------
__global__ __launch_bounds__(256) void pad_norms(const float* __restrict__ x,
    float* __restrict__ x4, float* __restrict__ nrm) {
  const int p = blockIdx.x * 256 + threadIdx.x;  // 16384
  float4 v;
  v.x = x[p * 3 + 0]; v.y = x[p * 3 + 1]; v.z = x[p * 3 + 2]; v.w = 0.f;
  *reinterpret_cast<float4*>(x4 + (size_t)p * 4) = v;
  nrm[p] = v.x * v.x + v.y * v.y + v.z * v.z;
}

// ---------------- all weight splits, fragment-order output ----------------
__global__ __launch_bounds__(256) void wsplit_all(const float* __restrict__ W1,
    const float* __restrict__ W2, const float* __restrict__ W3,
    const float* __restrict__ Wf,
    unsigned short* __restrict__ wb1, unsigned short* __restrict__ wb2,
    unsigned short* __restrict__ wb3,
    unsigned short* __restrict__ wfh, unsigned short* __restrict__ wfl) {
  const int id = blockIdx.x * 256 + threadIdx.x;  // 569344 total
  if (id < 524288) {
    const int row = id >> 9, c = id & 511;
    unsigned short h, l;
    split2(Wf[id], h, l);
    const size_t a = ((((size_t)(row >> 6)) * 64 + (c >> 3)) * 64 + (row & 63)) * 8 + (c & 7);
    wfh[a] = h; wfl[a] = l;
    return;
  }
  int id2 = id - 524288;
  const float* W; unsigned short* wb; int O, C;
  if (id2 < 4096)      { W = W1; wb = wb1; O = 64;  C = 64;  }
  else if (id2 < 12288){ W = W2; wb = wb2; O = 128; C = 64;  id2 -= 4096; }
  else                 { W = W3; wb = wb3; O = 256; C = 128; id2 -= 12288; }
  const int o = id2 / C, c = id2 % C;
  const int K8 = C >> 3;
  const float w1 = W[o * 2 * C + c];
  const float w2 = W[o * 2 * C + C + c];
  unsigned short h, l;
  const int r1 = o, rd = O + o;
  const size_t a1 = (((size_t)(r1 >> 6) * K8 + (c >> 3)) * 64 + (r1 & 63)) * 8 + (c & 7);
  const size_t ad = (((size_t)(rd >> 6) * K8 + (c >> 3)) * 64 + (rd & 63)) * 8 + (c & 7);
  split2(w1, h, l);
  wb[a1] = h; wb[2 * O * C + a1] = l;
  split2(w2 - w1, h, l);
  wb[ad] = h; wb[2 * O * C + ad] = l;
}

// ---------------- top-20 select on packed keys (R23 semantics) ------------------
__device__ __forceinline__ void select20(unsigned* __restrict__ srow,
    const int lane, int* __restrict__ op) {
  const int i31 = lane & 31;
  const int rot = 4 * (lane & 7);
  unsigned k1 = 0u, k2 = 0u;
#pragma unroll
  for (int q = 0; q < 8; ++q) {
    const uint4 v4 = *reinterpret_cast<const uint4*>(srow + lane * 32 + ((4 * q + rot) & 31));
    {
      const unsigned e = v4.x, lo = (k1 < e) ? k1 : e;
      k1 = (k1 > e) ? k1 : e; k2 = (k2 > lo) ? k2 : lo;
    }
    {
      const unsigned e = v4.y, lo = (k1 < e) ? k1 : e;
      k1 = (k1 > e) ? k1 : e; k2 = (k2 > lo) ? k2 : lo;
    }
    {
      const unsigned e = v4.z, lo = (k1 < e) ? k1 : e;
      k1 = (k1 > e) ? k1 : e; k2 = (k2 > lo) ? k2 : lo;
    }
    {
      const unsigned e = v4.w, lo = (k1 < e) ? k1 : e;
      k1 = (k1 > e) ? k1 : e; k2 = (k2 > lo) ? k2 : lo;
    }
  }
  int mycol = 0;
#pragma unroll
  for (int r = 0; r < KK; ++r) {
    const unsigned wm = wavemaxu(k1);
    const unsigned long long bal = __ballot(k1 == wm);
    const int wl = bal ? (__ffsll(bal) - 1) : 0;
    const int mwin = 31 - (int)(wm & 31u);
    const int col = wl * 32 + mwin;
    if (lane == r) mycol = col;
    if (lane == 0) srow[wl * 32 + ((mwin + 4 * (wl & 7)) & 31)] = 0u;  // poke
    if (lane == wl) { k1 = k2; k2 = 0u; }
    // only a twice-popped winner can have k1==0 (real keys are never 0)
    if (__ballot(k1 == 0u)) {
      asm volatile("s_waitcnt lgkmcnt(0)" ::: "memory");  // drain pokes
      __builtin_amdgcn_sched_barrier(0);                  // rule #18 fence
      const unsigned e = srow[wl * 32 + ((i31 + 4 * (wl & 7)) & 31)];
      const unsigned nm = wavemaxu(e);                    // poked slots = 0
      if (lane == wl) k1 = nm;
    }
  }
  if (lane < KK) op[lane] = mycol;  // coalesced 20-lane store
}

// ---------------- fused dist+knn, L0 (C=3, fp32) ----------------
__global__ __launch_bounds__(1024) void fused_dist_knn0(const float* __restrict__ X4,
    const float* __restrict__ norms, int* __restrict__ idxout) {
  __shared__ unsigned sdist[16][2048];
  const int t = threadIdx.x, lane = t & 63, w = t >> 6;  // w: 0..15
  const int l15 = lane & 15, g4 = lane >> 4;
  const int bid = blockIdx.x;          // 1024
  const int b = bid & 7, g = bid >> 3; // XCD-batch affinity
  const int i0 = g * 16;

  float4 rx[4]; float ni[4];
#pragma unroll
  for (int e = 0; e < 4; ++e) {
    const int p = b * NP + i0 + g4 * 4 + e;
    rx[e] = *reinterpret_cast<const float4*>(X4 + (size_t)p * 4);
    ni[e] = norms[p];
  }

  for (int it = 0; it < 8; ++it) {
    const int jl = it * 256 + w * 16 + l15;
    const int p = b * NP + jl;
    const float4 cj = *reinterpret_cast<const float4*>(X4 + (size_t)p * 4);
    const float nj = norms[p];
    const int ps = PHYS(jl);
#pragma unroll
    for (int e = 0; e < 4; ++e) {
      float acc = fmaf(rx[e].x, cj.x, 0.f);
      acc = fmaf(rx[e].y, cj.y, acc);
      acc = fmaf(rx[e].z, cj.z, acc);
      sdist[g4 * 4 + e][ps] = packkey(2.f * acc - ni[e] - nj, jl);
    }
  }
  __syncthreads();

  select20(&sdist[w][0], lane, idxout + (size_t)(b * NP + i0 + w) * KK);
}

// ---------------- fused dist+knn (l>=1): MFMA 16x16x32, swizzled LDS ------------
template<int C>
__global__ __launch_bounds__(1024) void fused_dist_knn(const unsigned short* __restrict__ xh,
    const unsigned short* __restrict__ xl, int colbase,
    const float* __restrict__ norms, int* __restrict__ idxout) {
  constexpr int KB = C / 32;  // K-blocks per chain
  __shared__ unsigned sdist[16][2048];
  const int t = threadIdx.x, lane = t & 63, w = t >> 6;  // w: 0..15
  const int l15 = lane & 15, g4 = lane >> 4;
  const int bid = blockIdx.x;          // 1024
  const int b = bid & 7, g = bid >> 3; // XCD-batch affinity
  const int i0 = g * 16;
  const int ti = (b * NP + i0) >> 6;
  const int ir = i0 & 63;
  const int k8b = colbase >> 3;

  bf16x8 AH[KB], AL[KB];
#pragma unroll
  for (int kb = 0; kb < KB; ++kb) {
    const size_t a = (((size_t)ti * 64 + k8b + kb * 4 + g4) * 64 + ir + l15) * 8;
    AH[kb] = *reinterpret_cast<const bf16x8*>(xh + a);
    AL[kb] = *reinterpret_cast<const bf16x8*>(xl + a);
  }
  float ni[4];
#pragma unroll
  for (int e = 0; e < 4; ++e) ni[e] = norms[b * NP + i0 + g4 * 4 + e];

  for (int it = 0; it < 8; ++it) {
    const int j0 = it * 256 + w * 16;
    const int tj = (b * NP + j0) >> 6;
    const int jr = j0 & 63;
    bf16x8 BH[KB], BL[KB];
#pragma unroll
    for (int kb = 0; kb < KB; ++kb) {
      const size_t a = (((size_t)tj * 64 + k8b + kb * 4 + g4) * 64 + jr + l15) * 8;
      BH[kb] = *reinterpret_cast<const bf16x8*>(xh + a);
      BL[kb] = *reinterpret_cast<const bf16x8*>(xl + a);
    }
    f32x4 acc = {0.f, 0.f, 0.f, 0.f};
#pragma unroll
    for (int kb = 0; kb < KB; ++kb) {
      acc = MF16(AH[kb], BH[kb], acc);
      acc = MF16(AH[kb], BL[kb], acc);
      acc = MF16(AL[kb], BH[kb], acc);
    }
    const float nj = norms[b * NP + j0 + l15];
    const int ps = PHYS(j0 + l15);
#pragma unroll
    for (int e = 0; e < 4; ++e)
      sdist[g4 * 4 + e][ps] = packkey(2.f * acc[e] - ni[e] - nj, j0 + l15);
  }
  __syncthreads();

  select20(&sdist[w][0], lane, idxout + (size_t)(b * NP + i0 + w) * KK);
}

// ---------------- per-point GEMM, L0 (C=3, fp32 vector) ----------------
__global__ __launch_bounds__(256) void pt_gemm0(const float* __restrict__ x,
    const float* __restrict__ W, const float* __restrict__ bias,
    float* __restrict__ Y, float* __restrict__ T) {
  const int t = threadIdx.x;
  const int o = t & 63;
  const int g = blockIdx.x * 4 + (t >> 6);  // 0..16383
  const float x0 = x[(size_t)g * 3 + 0], x1 = x[(size_t)g * 3 + 1], x2 = x[(size_t)g * 3 + 2];
  const float w10 = W[o * 6 + 0], w11 = W[o * 6 + 1], w12 = W[o * 6 + 2];
  const float w20 = W[o * 6 + 3], w21 = W[o * 6 + 4], w22 = W[o * 6 + 5];
  Y[(size_t)g * 64 + o] = w10 * x0 + w11 * x1 + w12 * x2;
  T[(size_t)g * 64 + o] = (w20 - w10) * x0 + (w21 - w11) * x1 + (w22 - w12) * x2 + bias[o];
}

// ---------------- per-point GEMM (l>=1): 2 n-tiles/block, B-frag reuse ----------
template<int C, int O2>  // O2 = 2*O
__global__ __launch_bounds__(256) void pt_gemm(const unsigned short* __restrict__ xh,
    const unsigned short* __restrict__ xl, int colbase,
    const unsigned short* __restrict__ wch, const unsigned short* __restrict__ wcl,
    const float* __restrict__ bias, float* __restrict__ Y, float* __restrict__ T) {
  constexpr int K8 = C / 8;
  constexpr int H = K8 / 2;
  constexpr int O = O2 / 2;
  const int t = threadIdx.x, lane = t & 63, w = t >> 6;
  const int half = lane >> 5, l31 = lane & 31;
  const int rt = (w >> 1) * 32, tc = (w & 1) * 32;
  const int n0 = blockIdx.x * 128, o0 = blockIdx.y * 64;  // 2 n-tiles per block
  const int tn0 = n0 >> 6, tn1 = tn0 + 1, to = o0 >> 6;
  const int k8b = colbase >> 3;
  const int col = o0 + tc + l31;

  bf16x8 BH[H], BL[H];
#pragma unroll
  for (int ch = 0; ch < H; ++ch) {
    const size_t a = (((size_t)to * K8 + ch * 2 + half) * 64 + tc + l31) * 8;
    BH[ch] = *reinterpret_cast<const bf16x8*>(wch + a);
    BL[ch] = *reinterpret_cast<const bf16x8*>(wcl + a);
  }

  f32x16 acc0, acc1;
#pragma unroll
  for (int i = 0; i < 16; ++i) { acc0[i] = 0.f; acc1[i] = 0.f; }
#pragma unroll
  for (int ch = 0; ch < H; ++ch) {
    const size_t a0 = (((size_t)tn0 * 64 + k8b + ch * 2 + half) * 64 + rt + l31) * 8;
    const size_t a1 = (((size_t)tn1 * 64 + k8b + ch * 2 + half) * 64 + rt + l31) * 8;
    const bf16x8 ah0 = *reinterpret_cast<const bf16x8*>(xh + a0);
    const bf16x8 al0 = *reinterpret_cast<const bf16x8*>(xl + a0);
    const bf16x8 ah1 = *reinterpret_cast<const bf16x8*>(xh + a1);
    const bf16x8 al1 = *reinterpret_cast<const bf16x8*>(xl + a1);
    acc0 = MF(ah0, BH[ch], acc0); acc1 = MF(ah1, BH[ch], acc1);
    acc0 = MF(ah0, BL[ch], acc0); acc1 = MF(ah1, BL[ch], acc1);
    acc0 = MF(al0, BH[ch], acc0); acc1 = MF(al1, BH[ch], acc1);
  }

  if (col < O) {
#pragma unroll
    for (int i = 0; i < 16; ++i) {
      const int rr = rt + (i & 3) + 8 * (i >> 2) + 4 * half;
      Y[(size_t)(n0 + rr) * O + col] = acc0[i];
      Y[(size_t)(n0 + 64 + rr) * O + col] = acc1[i];
    }
  } else {
    const float bv = bias[col - O];
#pragma unroll
    for (int i = 0; i < 16; ++i) {
      const int rr = rt + (i & 3) + 8 * (i >> 2) + 4 * half;
      T[(size_t)(n0 + rr) * O + (col - O)] = acc0[i] + bv;
      T[(size_t)(n0 + 64 + rr) * O + (col - O)] = acc1[i] + bv;
    }
  }
}

// ---------------- edge reduce: max/sum/sumsq over gathered Y rows ----------------
template<int O, int PTS>
__global__ __launch_bounds__(256) void edge_reduce(const float* __restrict__ Y,
    const float* __restrict__ T, const int* __restrict__ idx,
    float* __restrict__ outmax, float* __restrict__ ssum, float* __restrict__ ssq) {
  constexpr int CQ = O / 4;      // channel-quad groups
  constexpr int NG = 256 / CQ;   // point groups per block
  constexpr int PPT = PTS / NG;  // points per thread
  constexpr int BPB = NP / PTS;  // blocks per batch (128)
  __shared__ int sidx[PTS * KK];
  __shared__ float sred[1024], qred[1024];
  const int t = threadIdx.x;
  const int cq = t % CQ, ng = t / CQ;
  const int c = cq * 4;
  const int bid = blockIdx.x;    // 1024 blocks total
  const int g0 = ((bid & 7) * BPB + (bid >> 3)) * PTS;  // XCD-affinity swizzle

  for (int i = t; i < PTS * KK; i += 256) sidx[i] = idx[(size_t)g0 * KK + i];
  __syncthreads();

  float s4[4] = {}, q4[4] = {};
#pragma unroll
  for (int pp = 0; pp < PPT; ++pp) {
    const int p = ng + pp * NG;
    const int g = g0 + p;
    const int base = (g >> 11) * NP;
    const float4 tv = *reinterpret_cast<const float4*>(T + (size_t)g * O + c);
    float4 vs[KK];
#pragma unroll
    for (int k = 0; k < KK; ++k)
      vs[k] = *reinterpret_cast<const float4*>(Y + (size_t)(base + sidx[p * KK + k]) * O + c);
    float m0 = -__builtin_inff(), m1 = m0, m2 = m0, m3 = m0;
#pragma unroll
    for (int k = 0; k < KK; ++k) {
      const float h0 = vs[k].x + tv.x, h1 = vs[k].y + tv.y;
      const float h2 = vs[k].z + tv.z, h3 = vs[k].w + tv.w;
      m0 = fmaxf(m0, h0); m1 = fmaxf(m1, h1); m2 = fmaxf(m2, h2); m3 = fmaxf(m3, h3);
      s4[0] += h0; s4[1] += h1; s4[2] += h2; s4[3] += h3;
      q4[0] = fmaf(h0, h0, q4[0]); q4[1] = fmaf(h1, h1, q4[1]);
      q4[2] = fmaf(h2, h2, q4[2]); q4[3] = fmaf(h3, h3, q4[3]);
    }
    float4 o4; o4.x = m0; o4.y = m1; o4.z = m2; o4.w = m3;
    *reinterpret_cast<float4*>(outmax + (size_t)g * O + c) = o4;
  }

#pragma unroll
  for (int j = 0; j < 4; ++j) { sred[t * 4 + j] = s4[j]; qred[t * 4 + j] = q4[j]; }
  __syncthreads();
  if (t < O) {
    const int cqr = t >> 2, jr = t & 3;
    float s = 0.f, q = 0.f;
#pragma unroll
    for (int n = 0; n < NG; ++n) {
      s += sred[(n * CQ + cqr) * 4 + jr];
      q += qred[(n * CQ + cqr) * 4 + jr];
    }
    atomicAdd(ssum + t, s);
    atomicAdd(ssq + t, q);
  }
}

// ---------------- bn + leaky relu -> fragment-order bf16 planes ----------------
template<int O, bool WN>
__global__ __launch_bounds__(256) void bnrelu_kernel(const float* __restrict__ fA,
    const float* __restrict__ ssum, const float* __restrict__ ssq,
    const float* __restrict__ g, const float* __restrict__ be,
    unsigned short* __restrict__ xh, unsigned short* __restrict__ xl, int colbase,
    float* __restrict__ nrm) {
  constexpr float INV = 1.0f / 327680.0f;  // B*N*K
  constexpr int K8 = O / 8;
  const int id = blockIdx.x * 256 + threadIdx.x;  // 16384*K8 items
  const int r = id & 63;
  const int k8loc = (id >> 6) % K8;
  const int tile = (id >> 6) / K8;
  const int n = tile * 64 + r;
  const int c0 = k8loc * 8;

  float hv[8];
  {
    const float4 p0 = *reinterpret_cast<const float4*>(fA + (size_t)n * O + c0);
    const float4 p1 = *reinterpret_cast<const float4*>(fA + (size_t)n * O + c0 + 4);
    hv[0] = p0.x; hv[1] = p0.y; hv[2] = p0.z; hv[3] = p0.w;
    hv[4] = p1.x; hv[5] = p1.y; hv[6] = p1.z; hv[7] = p1.w;
  }
  unsigned short hh[8], ll[8];
  float s = 0.f;
#pragma unroll
  for (int j = 0; j < 8; ++j) {
    const int col = c0 + j;
    const float m = ssum[col] * INV;
    const float v = ssq[col] * INV - m * m;
    const float sc = g[col] / sqrtf(v + 1e-5f);
    float val = (hv[j] - m) * sc + be[col];
    val = (val >= 0.f) ? val : 0.2f * val;
    split2(val, hh[j], ll[j]);
    const float recon = bff(hh[j]) + bff(ll[j]);
    s = fmaf(recon, recon, s);
  }
  const size_t ob = (((size_t)tile * 64 + (colbase >> 3) + k8loc) * 64 + r) * 8;
  uint4 ph, pl;
  ph.x = (unsigned)hh[0] | ((unsigned)hh[1] << 16);
  ph.y = (unsigned)hh[2] | ((unsigned)hh[3] << 16);
  ph.z = (unsigned)hh[4] | ((unsigned)hh[5] << 16);
  ph.w = (unsigned)hh[6] | ((unsigned)hh[7] << 16);
  pl.x = (unsigned)ll[0] | ((unsigned)ll[1] << 16);
  pl.y = (unsigned)ll[2] | ((unsigned)ll[3] << 16);
  pl.z = (unsigned)ll[4] | ((unsigned)ll[5] << 16);
  pl.w = (unsigned)ll[6] | ((unsigned)ll[7] << 16);
  *reinterpret_cast<uint4*>(xh + ob) = ph;
  *reinterpret_cast<uint4*>(xl + ob) = pl;
  if (WN) atomicAdd(nrm + n, s);
}

// ---------------- final conv + max pool: 2 n-tiles/block, B-frag reuse ----------
__global__ __launch_bounds__(256) void final_mfma(const unsigned short* __restrict__ xh,
    const unsigned short* __restrict__ wfh, unsigned* __restrict__ outenc) {
  __shared__ float fr[128];
  const int t = threadIdx.x, lane = t & 63, w = t >> 6;
  const int half = lane >> 5, l31 = lane & 31;
  const int rt = (w >> 1) * 32, tc = (w & 1) * 32;
  const int b = blockIdx.z, n0 = blockIdx.x * 128, o0 = blockIdx.y * 64;
  const int tn0 = (b * NP + n0) >> 6, tn1 = tn0 + 1, to = o0 >> 6;

  f32x16 acc0, acc1;
#pragma unroll
  for (int i = 0; i < 16; ++i) { acc0[i] = 0.f; acc1[i] = 0.f; }

  for (int cc = 0; cc < 4; ++cc) {  // 128 channels per chunk
    bf16x8 BH[8];
#pragma unroll
    for (int ch = 0; ch < 8; ++ch) {
      const int k8 = cc * 16 + ch * 2 + half;
      const size_t a = (((size_t)to * 64 + k8) * 64 + tc + l31) * 8;
      BH[ch] = *reinterpret_cast<const bf16x8*>(wfh + a);
    }
#pragma unroll
    for (int ch = 0; ch < 8; ++ch) {
      const int k8 = cc * 16 + ch * 2 + half;
      const size_t a0 = (((size_t)tn0 * 64 + k8) * 64 + rt + l31) * 8;
      const size_t a1 = (((size_t)tn1 * 64 + k8) * 64 + rt + l31) * 8;
      const bf16x8 ah0 = *reinterpret_cast<const bf16x8*>(xh + a0);
      const bf16x8 ah1 = *reinterpret_cast<const bf16x8*>(xh + a1);
      acc0 = MF(ah0, BH[ch], acc0);
      acc1 = MF(ah1, BH[ch], acc1);
    }
  }

  float M = fmaxf(acc0[0], acc1[0]);
#pragma unroll
  for (int i = 1; i < 16; ++i) M = fmaxf(M, fmaxf(acc0[i], acc1[i]));
  M = fmaxf(M, __shfl_xor(M, 32));
  fr[w * 32 + l31] = M;
  __syncthreads();
  if (t < 64) {
    const float Mc = fmaxf(fr[t], fr[64 + t]);
    const unsigned ub = __float_as_uint(Mc);
    const unsigned key = (ub & 0x80000000u) ? ~ub : (ub | 0x80000000u);
    atomicMax(outenc + b * 1024 + o0 + t, key);
  }
}

__global__ __launch_bounds__(256) void decode_kernel(const unsigned int* __restrict__ enc,
    const float* __restrict__ bf, float* __restrict__ out) {
  const int gid = blockIdx.x * 256 + threadIdx.x;  // 8192
  const unsigned key = enc[gid];
  const unsigned ubits = (key & 0x80000000u) ? (key & 0x7fffffffu) : ~key;
  out[gid] = __uint_as_float(ubits) + bf[gid & 1023];
}

// ---------------- launch ----------------
extern "C" void kernel_launch(void* const* d_in, const int* in_sizes, int n_in,
                              void* d_out, int out_size, void* d_ws, size_t ws_size,
                              hipStream_t stream) {
  (void)in_sizes; (void)n_in; (void)out_size; (void)ws_size;
  const float* x   = (const float*)d_in[0];
  const float* W0  = (const float*)d_in[1];
  const float* b0  = (const float*)d_in[2];
  const float* g0  = (const float*)d_in[3];
  const float* be0 = (const float*)d_in[4];
  const float* W1  = (const float*)d_in[5];
  const float* b1  = (const float*)d_in[6];
  const float* g1  = (const float*)d_in[7];
  const float* be1 = (const float*)d_in[8];
  const float* W2  = (const float*)d_in[9];
  const float* b2  = (const float*)d_in[10];
  const float* g2  = (const float*)d_in[11];
  const float* be2 = (const float*)d_in[12];
  const float* W3  = (const float*)d_in[13];
  const float* b3  = (const float*)d_in[14];
  const float* g3  = (const float*)d_in[15];
  const float* be3 = (const float*)d_in[16];
  const float* Wf  = (const float*)d_in[17];
  const float* bf  = (const float*)d_in[18];

  float* wsf = (float*)d_ws;
  int* idxb = (int*)d_ws;                        // 327,680 ints
  float* stats = wsf + 327680;                   // 2048
  float* nb = wsf + 329728;                      // 4 x 16384 norm buffers
  unsigned* outenc = (unsigned*)(wsf + 395264);  // 8192
  float* x4 = wsf + 403456;                      // 65536
  float* featA = wsf + 468992;                   // 16384*256
  float* negd = wsf + 4663296;                   // scratch region (Y/T)
  float* Yb = negd;
  float* Tb = negd + 4194304;
  unsigned short* xh = (unsigned short*)(wsf + 21440512);  // xT hi plane
  unsigned short* xl = xh + 8388608;                       // xT lo plane
  unsigned short* wb1 = xl + 8388608;            // 2*(2*64*64)   = 16384
  unsigned short* wb2 = wb1 + 16384;             // 2*(2*128*64)  = 32768
  unsigned short* wb3 = wb2 + 32768;             // 2*(2*256*128) = 131072
  unsigned short* wfh = wb3 + 131072;            // 1024*512
  unsigned short* wfl = wfh + 524288;

  float* normsA = nb, *normsB = nb + 16384, *normsC = nb + 32768, *normsD = nb + 49152;

  hipMemsetAsync(stats, 0, (2048 + 65536) * sizeof(float), stream);
  hipMemsetAsync(outenc, 0, 8192 * sizeof(unsigned), stream);

  const dim3 blk(256, 1, 1);
  const dim3 fblk(1024, 1, 1);
  const dim3 fgrid(1024, 1, 1);
  const dim3 ergrid(1024, 1, 1);

  pad_norms<<<dim3(64), blk, 0, stream>>>(x, x4, normsA);
  wsplit_all<<<dim3(2224), blk, 0, stream>>>(W1, W2, W3, Wf, wb1, wb2, wb3, wfh, wfl);

  // Layer 0 (C=3 -> 64, out cols [0,64))
  fused_dist_knn0<<<fgrid, fblk, 0, stream>>>(x4, normsA, idxb);
  pt_gemm0<<<dim3(4096), blk, 0, stream>>>(x, W0, b0, Yb, Tb);
  edge_reduce<64, 16><<<ergrid, blk, 0, stream>>>(Yb, Tb, idxb, featA, stats, stats + 256);
  bnrelu_kernel<64, true><<<dim3(512), blk, 0, stream>>>(featA, stats, stats + 256,
      g0, be0, xh, xl, 0, normsB);

  // Layer 1 (64 -> 64, in cols [0,64), out [64,128))
  fused_dist_knn<64><<<fgrid, fblk, 0, stream>>>(xh, xl, 0, normsB, idxb);
  pt_gemm<64, 128><<<dim3(128, 2), blk, 0, stream>>>(xh, xl, 0, wb1, wb1 + 8192, b1, Yb, Tb);
  edge_reduce<64, 16><<<ergrid, blk, 0, stream>>>(Yb, Tb, idxb, featA, stats + 512, stats + 768);
  bnrelu_kernel<64, true><<<dim3(512), blk, 0, stream>>>(featA, stats + 512, stats + 768,
      g1, be1, xh, xl, 64, normsC);

  // Layer 2 (64 -> 128, in cols [64,128), out [128,256))
  fused_dist_knn<64><<<fgrid, fblk, 0, stream>>>(xh, xl, 64, normsC, idxb);
  pt_gemm<64, 256><<<dim3(128, 4), blk, 0, stream>>>(xh, xl, 64, wb2, wb2 + 16384, b2, Yb, Tb);
  edge_reduce<128, 16><<<ergrid, blk, 0, stream>>>(Yb, Tb, idxb, featA, stats + 1024, stats + 1280);
  bnrelu_kernel<128, true><<<dim3(1024), blk, 0, stream>>>(featA, stats + 1024, stats + 1280,
      g2, be2, xh, xl, 128, normsD);

  // Layer 3 (128 -> 256, in cols [128,256), out [256,512))
  fused_dist_knn<128><<<fgrid, fblk, 0, stream>>>(xh, xl, 128, normsD, idxb);
  pt_gemm<128, 512><<<dim3(128, 8), blk, 0, stream>>>(xh, xl, 128, wb3, wb3 + 65536, b3, Yb, Tb);
  edge_reduce<256, 16><<<ergrid, blk, 0, stream>>>(Yb, Tb, idxb, featA, stats + 1536, stats + 1792);
  bnrelu_kernel<256, false><<<dim3(2048), blk, 0, stream>>>(featA, stats + 1536, stats + 1792,
      g3, be3, xh, xl, 256, nullptr);

  // Final 1x1 conv + global max pool (single-plane, 2 n-tiles/block)
  final_mfma<<<dim3(16, 16, 8), blk, 0, stream>>>(xh, wfh, outenc);
  decode_kernel<<<dim3(32), blk, 0, stream>>>(outenc, bf, (float*)d_out);
}

// Round 17
// 472.512 us; speedup vs baseline: 1.1165x; 1.0112x over previous
//
#include <hip/hip_runtime.h>
#include <cstdint>
#include <cstddef>

// DGCNN forward. R28: R27 + address strength-reduction in the fused kernels.
// Accounting of fused_dist_knn's 67us: VALU issue 27us, of which ~12us is
// compute-phase 64-bit address recomputation (16 B-frag loads/iter from
// scratch) + per-iter PHYS/packkey. The loop is perfectly strength-reducible:
// jr=(w*16)&63 is it-invariant, tj increments by exactly 4/iter (pointer
// stride 131072 elems, constant under unroll), PHYS(jl)=PHYS(w*16+l15)+it*256
// exactly, packkey pos bits it-invariant. R28 hoists all of it; packkey flip
// as 3-inst u^(sext|0x80000000) (bit-identical). No semantic change anywhere.

constexpr int NB = 8;
constexpr int NP = 2048;
constexpr int KK = 20;

typedef short bf16x8 __attribute__((ext_vector_type(8)));
typedef float f32x16 __attribute__((ext_vector_type(16)));
typedef float f32x4 __attribute__((ext_vector_type(4)));

__device__ __forceinline__ f32x16 MF(bf16x8 a, bf16x8 b, f32x16 c) {
  return __builtin_amdgcn_mfma_f32_32x32x16_bf16(a, b, c, 0, 0, 0);
}
__device__ __forceinline__ f32x4 MF16(bf16x8 a, bf16x8 b, f32x4 c) {
  return __builtin_amdgcn_mfma_f32_16x16x32_bf16(a, b, c, 0, 0, 0);
}
__device__ __forceinline__ unsigned short bfh(float f) {
  return (unsigned short)(__float_as_uint(f) >> 16);  // truncating bf16
}
__device__ __forceinline__ float bff(unsigned short u) {
  return __uint_as_float(((unsigned)u) << 16);
}
__device__ __forceinline__ void split2(float v, unsigned short& h, unsigned short& l) {
  h = bfh(v); l = bfh(v - bff(h));
}
// rotation swizzle: rotate within each 32-col segment by 4*(owner&7) words.
__device__ __forceinline__ int PHYS(int c) {
  return (c & ~31) | ((c + 4 * ((c >> 5) & 7)) & 31);
}
// monotone key: flip float bits (3-inst form), embed (31 - pos) in low 5 bits.
__device__ __forceinline__ unsigned packkey(float d, int col) {
  const unsigned u = __float_as_uint(d);
  const unsigned k = u ^ (((unsigned)((int)u >> 31)) | 0x80000000u);
  return (k & ~31u) | (31u - ((unsigned)col & 31u));
}

// full-wave unsigned max via DPP (identity 0); uniform result in all lanes.
__device__ __forceinline__ unsigned wavemaxu(unsigned v) {
  int x = (int)v, t;
  t = __builtin_amdgcn_update_dpp(0, x, 0x111, 0xf, 0xf, false);  // row_shr:1
  x = (int)(((unsigned)x > (unsigned)t) ? (unsigned)x : (unsigned)t);
  t = __builtin_amdgcn_update_dpp(0, x, 0x112, 0xf, 0xf, false);  // row_shr:2
  x = (int)(((unsigned)x > (unsigned)t) ? (unsigned)x : (unsigned)t);
  t = __builtin_amdgcn_update_dpp(0, x, 0x114, 0xf, 0xf, false);  // row_shr:4
  x = (int)(((unsigned)x > (unsigned)t) ? (unsigned)x : (unsigned)t);
  t = __builtin_amdgcn_update_dpp(0, x, 0x118, 0xf, 0xf, false);  // row_shr:8
  x = (int)(((unsigned)x > (unsigned)t) ? (unsigned)x : (unsigned)t);
  t = __builtin_amdgcn_update_dpp(0, x, 0x142, 0xf, 0xf, false);  // row_bcast15
  x = (int)(((unsigned)x > (unsigned)t) ? (unsigned)x : (unsigned)t);
  t = __builtin_amdgcn_update_dpp(0, x, 0x143, 0xf, 0xf, false);  // row_bcast31
  x = (int)(((unsigned)x > (unsigned)t) ? (unsigned)x : (unsigned)t);
  return (unsigned)__builtin_amdgcn_readlane(x, 63);
}

// ---------------- pad x -> x4, plus L0 norms ----------------
__global__ __launch_bounds__(256) void pad_norms(const float* __restrict__ x,
    float* __restrict__ x4, float* __restrict__ nrm) {
  const int p = blockIdx.x * 256 + threadIdx.x;  // 16384
  float4 v;
  v.x = x[p * 3 + 0]; v.y = x[p * 3 + 1]; v.z = x[p * 3 + 2]; v.w = 0.f;
  *reinterpret_cast<float4*>(x4 + (size_t)p * 4) = v;
  nrm[p] = v.x * v.x + v.y * v.y + v.z * v.z;
}

// ---------------- all weight splits, fragment-order output ----------------
__global__ __launch_bounds__(256) void wsplit_all(const float* __restrict__ W1,
    const float* __restrict__ W2, const float* __restrict__ W3,
    const float* __restrict__ Wf,
    unsigned short* __restrict__ wb1, unsigned short* __restrict__ wb2,
    unsigned short* __restrict__ wb3,
    unsigned short* __restrict__ wfh, unsigned short* __restrict__ wfl) {
  const int id = blockIdx.x * 256 + threadIdx.x;  // 569344 total
  if (id < 524288) {
    const int row = id >> 9, c = id & 511;
    unsigned short h, l;
    split2(Wf[id], h, l);
    const size_t a = ((((size_t)(row >> 6)) * 64 + (c >> 3)) * 64 + (row & 63)) * 8 + (c & 7);
    wfh[a] = h; wfl[a] = l;
    return;
  }
  int id2 = id - 524288;
  const float* W; unsigned short* wb; int O, C;
  if (id2 < 4096)      { W = W1; wb = wb1; O = 64;  C = 64;  }
  else if (id2 < 12288){ W = W2; wb = wb2; O = 128; C = 64;  id2 -= 4096; }
  else                 { W = W3; wb = wb3; O = 256; C = 128; id2 -= 12288; }
  const int o = id2 / C, c = id2 % C;
  const int K8 = C >> 3;
  const float w1 = W[o * 2 * C + c];
  const float w2 = W[o * 2 * C + C + c];
  unsigned short h, l;
  const int r1 = o, rd = O + o;
  const size_t a1 = (((size_t)(r1 >> 6) * K8 + (c >> 3)) * 64 + (r1 & 63)) * 8 + (c & 7);
  const size_t ad = (((size_t)(rd >> 6) * K8 + (c >> 3)) * 64 + (rd & 63)) * 8 + (c & 7);
  split2(w1, h, l);
  wb[a1] = h; wb[2 * O * C + a1] = l;
  split2(w2 - w1, h, l);
  wb[ad] = h; wb[2 * O * C + ad] = l;
}

// ---------------- top-20 select on packed keys (R23 semantics) ------------------
__device__ __forceinline__ void select20(unsigned* __restrict__ srow,
    const int lane, int* __restrict__ op) {
  const int i31 = lane & 31;
  const int rot = 4 * (lane & 7);
  unsigned k1 = 0u, k2 = 0u;
#pragma unroll
  for (int q = 0; q < 8; ++q) {
    const uint4 v4 = *reinterpret_cast<const uint4*>(srow + lane * 32 + ((4 * q + rot) & 31));
    {
      const unsigned e = v4.x, lo = (k1 < e) ? k1 : e;
      k1 = (k1 > e) ? k1 : e; k2 = (k2 > lo) ? k2 : lo;
    }
    {
      const unsigned e = v4.y, lo = (k1 < e) ? k1 : e;
      k1 = (k1 > e) ? k1 : e; k2 = (k2 > lo) ? k2 : lo;
    }
    {
      const unsigned e = v4.z, lo = (k1 < e) ? k1 : e;
      k1 = (k1 > e) ? k1 : e; k2 = (k2 > lo) ? k2 : lo;
    }
    {
      const unsigned e = v4.w, lo = (k1 < e) ? k1 : e;
      k1 = (k1 > e) ? k1 : e; k2 = (k2 > lo) ? k2 : lo;
    }
  }
  int mycol = 0;
#pragma unroll
  for (int r = 0; r < KK; ++r) {
    const unsigned wm = wavemaxu(k1);
    const unsigned long long bal = __ballot(k1 == wm);
    const int wl = bal ? (__ffsll(bal) - 1) : 0;
    const int mwin = 31 - (int)(wm & 31u);
    const int col = wl * 32 + mwin;
    if (lane == r) mycol = col;
    if (lane == 0) srow[wl * 32 + ((mwin + 4 * (wl & 7)) & 31)] = 0u;  // poke
    if (lane == wl) { k1 = k2; k2 = 0u; }
    // only a twice-popped winner can have k1==0 (real keys are never 0)
    if (__ballot(k1 == 0u)) {
      asm volatile("s_waitcnt lgkmcnt(0)" ::: "memory");  // drain pokes
      __builtin_amdgcn_sched_barrier(0);                  // rule #18 fence
      const unsigned e = srow[wl * 32 + ((i31 + 4 * (wl & 7)) & 31)];
      const unsigned nm = wavemaxu(e);                    // poked slots = 0
      if (lane == wl) k1 = nm;
    }
  }
  if (lane < KK) op[lane] = mycol;  // coalesced 20-lane store
}

// ---------------- fused dist+knn, L0 (C=3, fp32) ----------------
__global__ __launch_bounds__(1024) void fused_dist_knn0(const float* __restrict__ X4,
    const float* __restrict__ norms, int* __restrict__ idxout) {
  __shared__ unsigned sdist[16][2048];
  const int t = threadIdx.x, lane = t & 63, w = t >> 6;  // w: 0..15
  const int l15 = lane & 15, g4 = lane >> 4;
  const int bid = blockIdx.x;          // 1024
  const int b = bid & 7, g = bid >> 3; // XCD-batch affinity
  const int i0 = g * 16;

  float4 rx[4]; float ni[4];
#pragma unroll
  for (int e = 0; e < 4; ++e) {
    const int p = b * NP + i0 + g4 * 4 + e;
    rx[e] = *reinterpret_cast<const float4*>(X4 + (size_t)p * 4);
    ni[e] = norms[p];
  }

  // hoisted j-side bases: jl = it*256 + (w*16+l15); strides are constant
  const int jl0 = w * 16 + l15;
  const float* px = X4 + (size_t)(b * NP + jl0) * 4;
  const float* pn = norms + b * NP + jl0;
  const int ps0 = PHYS(jl0);
#pragma unroll
  for (int it = 0; it < 8; ++it) {
    const float4 cj = *reinterpret_cast<const float4*>(px + (size_t)it * 1024);
    const float nj = pn[it * 256];
    const int ps = ps0 + it * 256;
#pragma unroll
    for (int e = 0; e < 4; ++e) {
      float acc = fmaf(rx[e].x, cj.x, 0.f);
      acc = fmaf(rx[e].y, cj.y, acc);
      acc = fmaf(rx[e].z, cj.z, acc);
      sdist[g4 * 4 + e][ps] = packkey(2.f * acc - ni[e] - nj, jl0);
    }
  }
  __syncthreads();

  select20(&sdist[w][0], lane, idxout + (size_t)(b * NP + i0 + w) * KK);
}

// ---------------- fused dist+knn (l>=1): MFMA 16x16x32, hoisted addressing ------
template<int C>
__global__ __launch_bounds__(1024) void fused_dist_knn(const unsigned short* __restrict__ xh,
    const unsigned short* __restrict__ xl, int colbase,
    const float* __restrict__ norms, int* __restrict__ idxout) {
  constexpr int KB = C / 32;  // K-blocks per chain
  __shared__ unsigned sdist[16][2048];
  const int t = threadIdx.x, lane = t & 63, w = t >> 6;  // w: 0..15
  const int l15 = lane & 15, g4 = lane >> 4;
  const int bid = blockIdx.x;          // 1024
  const int b = bid & 7, g = bid >> 3; // XCD-batch affinity
  const int i0 = g * 16;
  const int ti = (b * NP + i0) >> 6;
  const int ir = i0 & 63;
  const int k8b = colbase >> 3;

  bf16x8 AH[KB], AL[KB];
#pragma unroll
  for (int kb = 0; kb < KB; ++kb) {
    const size_t a = (((size_t)ti * 64 + k8b + kb * 4 + g4) * 64 + ir + l15) * 8;
    AH[kb] = *reinterpret_cast<const bf16x8*>(xh + a);
    AL[kb] = *reinterpret_cast<const bf16x8*>(xl + a);
  }
  float ni[4];
#pragma unroll
  for (int e = 0; e < 4; ++e) ni[e] = norms[b * NP + i0 + g4 * 4 + e];

  // hoisted j-side bases: jr=(w*16)&63 is it-invariant; tj += 4/iter
  // -> pointer stride 4*64*64*8 = 131072 elements per iteration.
  const int tj0 = (b * NP + w * 16) >> 6;
  const int jr0 = (w * 16) & 63;
  const unsigned short* pbh[KB];
  const unsigned short* pbl[KB];
#pragma unroll
  for (int kb = 0; kb < KB; ++kb) {
    const size_t a = (((size_t)tj0 * 64 + k8b + kb * 4 + g4) * 64 + jr0 + l15) * 8;
    pbh[kb] = xh + a;
    pbl[kb] = xl + a;
  }
  const int jl0 = w * 16 + l15;
  const float* pnj = norms + b * NP + jl0;
  const int ps0 = PHYS(jl0);

#pragma unroll
  for (int it = 0; it < 8; ++it) {
    bf16x8 BH[KB], BL[KB];
#pragma unroll
    for (int kb = 0; kb < KB; ++kb) {
      BH[kb] = *reinterpret_cast<const bf16x8*>(pbh[kb] + (size_t)it * 131072);
      BL[kb] = *reinterpret_cast<const bf16x8*>(pbl[kb] + (size_t)it * 131072);
    }
    f32x4 acc = {0.f, 0.f, 0.f, 0.f};
#pragma unroll
    for (int kb = 0; kb < KB; ++kb) {
      acc = MF16(AH[kb], BH[kb], acc);
      acc = MF16(AH[kb], BL[kb], acc);
      acc = MF16(AL[kb], BH[kb], acc);
    }
    const float nj = pnj[it * 256];
    const int ps = ps0 + it * 256;
#pragma unroll
    for (int e = 0; e < 4; ++e)
      sdist[g4 * 4 + e][ps] = packkey(2.f * acc[e] - ni[e] - nj, jl0);
  }
  __syncthreads();

  select20(&sdist[w][0], lane, idxout + (size_t)(b * NP + i0 + w) * KK);
}

// ---------------- per-point GEMM, L0 (C=3, fp32 vector) ----------------
__global__ __launch_bounds__(256) void pt_gemm0(const float* __restrict__ x,
    const float* __restrict__ W, const float* __restrict__ bias,
    float* __restrict__ Y, float* __restrict__ T) {
  const int t = threadIdx.x;
  const int o = t & 63;
  const int g = blockIdx.x * 4 + (t >> 6);  // 0..16383
  const float x0 = x[(size_t)g * 3 + 0], x1 = x[(size_t)g * 3 + 1], x2 = x[(size_t)g * 3 + 2];
  const float w10 = W[o * 6 + 0], w11 = W[o * 6 + 1], w12 = W[o * 6 + 2];
  const float w20 = W[o * 6 + 3], w21 = W[o * 6 + 4], w22 = W[o * 6 + 5];
  Y[(size_t)g * 64 + o] = w10 * x0 + w11 * x1 + w12 * x2;
  T[(size_t)g * 64 + o] = (w20 - w10) * x0 + (w21 - w11) * x1 + (w22 - w12) * x2 + bias[o];
}

// ---------------- per-point GEMM (l>=1): 2 n-tiles/block, B-frag reuse ----------
template<int C, int O2>  // O2 = 2*O
__global__ __launch_bounds__(256) void pt_gemm(const unsigned short* __restrict__ xh,
    const unsigned short* __restrict__ xl, int colbase,
    const unsigned short* __restrict__ wch, const unsigned short* __restrict__ wcl,
    const float* __restrict__ bias, float* __restrict__ Y, float* __restrict__ T) {
  constexpr int K8 = C / 8;
  constexpr int H = K8 / 2;
  constexpr int O = O2 / 2;
  const int t = threadIdx.x, lane = t & 63, w = t >> 6;
  const int half = lane >> 5, l31 = lane & 31;
  const int rt = (w >> 1) * 32, tc = (w & 1) * 32;
  const int n0 = blockIdx.x * 128, o0 = blockIdx.y * 64;  // 2 n-tiles per block
  const int tn0 = n0 >> 6, tn1 = tn0 + 1, to = o0 >> 6;
  const int k8b = colbase >> 3;
  const int col = o0 + tc + l31;

  bf16x8 BH[H], BL[H];
#pragma unroll
  for (int ch = 0; ch < H; ++ch) {
    const size_t a = (((size_t)to * K8 + ch * 2 + half) * 64 + tc + l31) * 8;
    BH[ch] = *reinterpret_cast<const bf16x8*>(wch + a);
    BL[ch] = *reinterpret_cast<const bf16x8*>(wcl + a);
  }

  f32x16 acc0, acc1;
#pragma unroll
  for (int i = 0; i < 16; ++i) { acc0[i] = 0.f; acc1[i] = 0.f; }
#pragma unroll
  for (int ch = 0; ch < H; ++ch) {
    const size_t a0 = (((size_t)tn0 * 64 + k8b + ch * 2 + half) * 64 + rt + l31) * 8;
    const size_t a1 = (((size_t)tn1 * 64 + k8b + ch * 2 + half) * 64 + rt + l31) * 8;
    const bf16x8 ah0 = *reinterpret_cast<const bf16x8*>(xh + a0);
    const bf16x8 al0 = *reinterpret_cast<const bf16x8*>(xl + a0);
    const bf16x8 ah1 = *reinterpret_cast<const bf16x8*>(xh + a1);
    const bf16x8 al1 = *reinterpret_cast<const bf16x8*>(xl + a1);
    acc0 = MF(ah0, BH[ch], acc0); acc1 = MF(ah1, BH[ch], acc1);
    acc0 = MF(ah0, BL[ch], acc0); acc1 = MF(ah1, BL[ch], acc1);
    acc0 = MF(al0, BH[ch], acc0); acc1 = MF(al1, BH[ch], acc1);
  }

  if (col < O) {
#pragma unroll
    for (int i = 0; i < 16; ++i) {
      const int rr = rt + (i & 3) + 8 * (i >> 2) + 4 * half;
      Y[(size_t)(n0 + rr) * O + col] = acc0[i];
      Y[(size_t)(n0 + 64 + rr) * O + col] = acc1[i];
    }
  } else {
    const float bv = bias[col - O];
#pragma unroll
    for (int i = 0; i < 16; ++i) {
      const int rr = rt + (i & 3) + 8 * (i >> 2) + 4 * half;
      T[(size_t)(n0 + rr) * O + (col - O)] = acc0[i] + bv;
      T[(size_t)(n0 + 64 + rr) * O + (col - O)] = acc1[i] + bv;
    }
  }
}

// ---------------- edge reduce: max/sum/sumsq over gathered Y rows ----------------
template<int O, int PTS>
__global__ __launch_bounds__(256) void edge_reduce(const float* __restrict__ Y,
    const float* __restrict__ T, const int* __restrict__ idx,
    float* __restrict__ outmax, float* __restrict__ ssum, float* __restrict__ ssq) {
  constexpr int CQ = O / 4;      // channel-quad groups
  constexpr int NG = 256 / CQ;   // point groups per block
  constexpr int PPT = PTS / NG;  // points per thread
  constexpr int BPB = NP / PTS;  // blocks per batch (128)
  __shared__ int sidx[PTS * KK];
  __shared__ float sred[1024], qred[1024];
  const int t = threadIdx.x;
  const int cq = t % CQ, ng = t / CQ;
  const int c = cq * 4;
  const int bid = blockIdx.x;    // 1024 blocks total
  const int g0 = ((bid & 7) * BPB + (bid >> 3)) * PTS;  // XCD-affinity swizzle

  for (int i = t; i < PTS * KK; i += 256) sidx[i] = idx[(size_t)g0 * KK + i];
  __syncthreads();

  float s4[4] = {}, q4[4] = {};
#pragma unroll
  for (int pp = 0; pp < PPT; ++pp) {
    const int p = ng + pp * NG;
    const int g = g0 + p;
    const int base = (g >> 11) * NP;
    const float4 tv = *reinterpret_cast<const float4*>(T + (size_t)g * O + c);
    float4 vs[KK];
#pragma unroll
    for (int k = 0; k < KK; ++k)
      vs[k] = *reinterpret_cast<const float4*>(Y + (size_t)(base + sidx[p * KK + k]) * O + c);
    float m0 = -__builtin_inff(), m1 = m0, m2 = m0, m3 = m0;
#pragma unroll
    for (int k = 0; k < KK; ++k) {
      const float h0 = vs[k].x + tv.x, h1 = vs[k].y + tv.y;
      const float h2 = vs[k].z + tv.z, h3 = vs[k].w + tv.w;
      m0 = fmaxf(m0, h0); m1 = fmaxf(m1, h1); m2 = fmaxf(m2, h2); m3 = fmaxf(m3, h3);
      s4[0] += h0; s4[1] += h1; s4[2] += h2; s4[3] += h3;
      q4[0] = fmaf(h0, h0, q4[0]); q4[1] = fmaf(h1, h1, q4[1]);
      q4[2] = fmaf(h2, h2, q4[2]); q4[3] = fmaf(h3, h3, q4[3]);
    }
    float4 o4; o4.x = m0; o4.y = m1; o4.z = m2; o4.w = m3;
    *reinterpret_cast<float4*>(outmax + (size_t)g * O + c) = o4;
  }

#pragma unroll
  for (int j = 0; j < 4; ++j) { sred[t * 4 + j] = s4[j]; qred[t * 4 + j] = q4[j]; }
  __syncthreads();
  if (t < O) {
    const int cqr = t >> 2, jr = t & 3;
    float s = 0.f, q = 0.f;
#pragma unroll
    for (int n = 0; n < NG; ++n) {
      s += sred[(n * CQ + cqr) * 4 + jr];
      q += qred[(n * CQ + cqr) * 4 + jr];
    }
    atomicAdd(ssum + t, s);
    atomicAdd(ssq + t, q);
  }
}

// ---------------- bn + leaky relu -> fragment-order bf16 planes ----------------
template<int O, bool WN>
__global__ __launch_bounds__(256) void bnrelu_kernel(const float* __restrict__ fA,
    const float* __restrict__ ssum, const float* __restrict__ ssq,
    const float* __restrict__ g, const float* __restrict__ be,
    unsigned short* __restrict__ xh, unsigned short* __restrict__ xl, int colbase,
    float* __restrict__ nrm) {
  constexpr float INV = 1.0f / 327680.0f;  // B*N*K
  constexpr int K8 = O / 8;
  const int id = blockIdx.x * 256 + threadIdx.x;  // 16384*K8 items
  const int r = id & 63;
  const int k8loc = (id >> 6) % K8;
  const int tile = (id >> 6) / K8;
  const int n = tile * 64 + r;
  const int c0 = k8loc * 8;

  float hv[8];
  {
    const float4 p0 = *reinterpret_cast<const float4*>(fA + (size_t)n * O + c0);
    const float4 p1 = *reinterpret_cast<const float4*>(fA + (size_t)n * O + c0 + 4);
    hv[0] = p0.x; hv[1] = p0.y; hv[2] = p0.z; hv[3] = p0.w;
    hv[4] = p1.x; hv[5] = p1.y; hv[6] = p1.z; hv[7] = p1.w;
  }
  unsigned short hh[8], ll[8];
  float s = 0.f;
#pragma unroll
  for (int j = 0; j < 8; ++j) {
    const int col = c0 + j;
    const float m = ssum[col] * INV;
    const float v = ssq[col] * INV - m * m;
    const float sc = g[col] / sqrtf(v + 1e-5f);
    float val = (hv[j] - m) * sc + be[col];
    val = (val >= 0.f) ? val : 0.2f * val;
    split2(val, hh[j], ll[j]);
    const float recon = bff(hh[j]) + bff(ll[j]);
    s = fmaf(recon, recon, s);
  }
  const size_t ob = (((size_t)tile * 64 + (colbase >> 3) + k8loc) * 64 + r) * 8;
  uint4 ph, pl;
  ph.x = (unsigned)hh[0] | ((unsigned)hh[1] << 16);
  ph.y = (unsigned)hh[2] | ((unsigned)hh[3] << 16);
  ph.z = (unsigned)hh[4] | ((unsigned)hh[5] << 16);
  ph.w = (unsigned)hh[6] | ((unsigned)hh[7] << 16);
  pl.x = (unsigned)ll[0] | ((unsigned)ll[1] << 16);
  pl.y = (unsigned)ll[2] | ((unsigned)ll[3] << 16);
  pl.z = (unsigned)ll[4] | ((unsigned)ll[5] << 16);
  pl.w = (unsigned)ll[6] | ((unsigned)ll[7] << 16);
  *reinterpret_cast<uint4*>(xh + ob) = ph;
  *reinterpret_cast<uint4*>(xl + ob) = pl;
  if (WN) atomicAdd(nrm + n, s);
}

// ---------------- final conv + max pool: 2 n-tiles/block, B-frag reuse ----------
__global__ __launch_bounds__(256) void final_mfma(const unsigned short* __restrict__ xh,
    const unsigned short* __restrict__ wfh, unsigned* __restrict__ outenc) {
  __shared__ float fr[128];
  const int t = threadIdx.x, lane = t & 63, w = t >> 6;
  const int half = lane >> 5, l31 = lane & 31;
  const int rt = (w >> 1) * 32, tc = (w & 1) * 32;
  const int b = blockIdx.z, n0 = blockIdx.x * 128, o0 = blockIdx.y * 64;
  const int tn0 = (b * NP + n0) >> 6, tn1 = tn0 + 1, to = o0 >> 6;

  f32x16 acc0, acc1;
#pragma unroll
  for (int i = 0; i < 16; ++i) { acc0[i] = 0.f; acc1[i] = 0.f; }

#pragma unroll
  for (int cc = 0; cc < 4; ++cc) {  // 128 channels per chunk
    bf16x8 BH[8];
#pragma unroll
    for (int ch = 0; ch < 8; ++ch) {
      const int k8 = cc * 16 + ch * 2 + half;
      const size_t a = (((size_t)to * 64 + k8) * 64 + tc + l31) * 8;
      BH[ch] = *reinterpret_cast<const bf16x8*>(wfh + a);
    }
#pragma unroll
    for (int ch = 0; ch < 8; ++ch) {
      const int k8 = cc * 16 + ch * 2 + half;
      const size_t a0 = (((size_t)tn0 * 64 + k8) * 64 + rt + l31) * 8;
      const size_t a1 = (((size_t)tn1 * 64 + k8) * 64 + rt + l31) * 8;
      const bf16x8 ah0 = *reinterpret_cast<const bf16x8*>(xh + a0);
      const bf16x8 ah1 = *reinterpret_cast<const bf16x8*>(xh + a1);
      acc0 = MF(ah0, BH[ch], acc0);
      acc1 = MF(ah1, BH[ch], acc1);
    }
  }

  float M = fmaxf(acc0[0], acc1[0]);
#pragma unroll
  for (int i = 1; i < 16; ++i) M = fmaxf(M, fmaxf(acc0[i], acc1[i]));
  M = fmaxf(M, __shfl_xor(M, 32));
  fr[w * 32 + l31] = M;
  __syncthreads();
  if (t < 64) {
    const float Mc = fmaxf(fr[t], fr[64 + t]);
    const unsigned ub = __float_as_uint(Mc);
    const unsigned key = (ub & 0x80000000u) ? ~ub : (ub | 0x80000000u);
    atomicMax(outenc + b * 1024 + o0 + t, key);
  }
}

__global__ __launch_bounds__(256) void decode_kernel(const unsigned int* __restrict__ enc,
    const float* __restrict__ bf, float* __restrict__ out) {
  const int gid = blockIdx.x * 256 + threadIdx.x;  // 8192
  const unsigned key = enc[gid];
  const unsigned ubits = (key & 0x80000000u) ? (key & 0x7fffffffu) : ~key;
  out[gid] = __uint_as_float(ubits) + bf[gid & 1023];
}

// ---------------- launch ----------------
extern "C" void kernel_launch(void* const* d_in, const int* in_sizes, int n_in,
                              void* d_out, int out_size, void* d_ws, size_t ws_size,
                              hipStream_t stream) {
  (void)in_sizes; (void)n_in; (void)out_size; (void)ws_size;
  const float* x   = (const float*)d_in[0];
  const float* W0  = (const float*)d_in[1];
  const float* b0  = (const float*)d_in[2];
  const float* g0  = (const float*)d_in[3];
  const float* be0 = (const float*)d_in[4];
  const float* W1  = (const float*)d_in[5];
  const float* b1  = (const float*)d_in[6];
  const float* g1  = (const float*)d_in[7];
  const float* be1 = (const float*)d_in[8];
  const float* W2  = (const float*)d_in[9];
  const float* b2  = (const float*)d_in[10];
  const float* g2  = (const float*)d_in[11];
  const float* be2 = (const float*)d_in[12];
  const float* W3  = (const float*)d_in[13];
  const float* b3  = (const float*)d_in[14];
  const float* g3  = (const float*)d_in[15];
  const float* be3 = (const float*)d_in[16];
  const float* Wf  = (const float*)d_in[17];
  const float* bf  = (const float*)d_in[18];

  float* wsf = (float*)d_ws;
  int* idxb = (int*)d_ws;                        // 327,680 ints
  float* stats = wsf + 327680;                   // 2048
  float* nb = wsf + 329728;                      // 4 x 16384 norm buffers
  unsigned* outenc = (unsigned*)(wsf + 395264);  // 8192
  float* x4 = wsf + 403456;                      // 65536
  float* featA = wsf + 468992;                   // 16384*256
  float* negd = wsf + 4663296;                   // scratch region (Y/T)
  float* Yb = negd;
  float* Tb = negd + 4194304;
  unsigned short* xh = (unsigned short*)(wsf + 21440512);  // xT hi plane
  unsigned short* xl = xh + 8388608;                       // xT lo plane
  unsigned short* wb1 = xl + 8388608;            // 2*(2*64*64)   = 16384
  unsigned short* wb2 = wb1 + 16384;             // 2*(2*128*64)  = 32768
  unsigned short* wb3 = wb2 + 32768;             // 2*(2*256*128) = 131072
  unsigned short* wfh = wb3 + 131072;            // 1024*512
  unsigned short* wfl = wfh + 524288;

  float* normsA = nb, *normsB = nb + 16384, *normsC = nb + 32768, *normsD = nb + 49152;

  hipMemsetAsync(stats, 0, (2048 + 65536) * sizeof(float), stream);
  hipMemsetAsync(outenc, 0, 8192 * sizeof(unsigned), stream);

  const dim3 blk(256, 1, 1);
  const dim3 fblk(1024, 1, 1);
  const dim3 fgrid(1024, 1, 1);
  const dim3 ergrid(1024, 1, 1);

  pad_norms<<<dim3(64), blk, 0, stream>>>(x, x4, normsA);
  wsplit_all<<<dim3(2224), blk, 0, stream>>>(W1, W2, W3, Wf, wb1, wb2, wb3, wfh, wfl);

  // Layer 0 (C=3 -> 64, out cols [0,64))
  fused_dist_knn0<<<fgrid, fblk, 0, stream>>>(x4, normsA, idxb);
  pt_gemm0<<<dim3(4096), blk, 0, stream>>>(x, W0, b0, Yb, Tb);
  edge_reduce<64, 16><<<ergrid, blk, 0, stream>>>(Yb, Tb, idxb, featA, stats, stats + 256);
  bnrelu_kernel<64, true><<<dim3(512), blk, 0, stream>>>(featA, stats, stats + 256,
      g0, be0, xh, xl, 0, normsB);

  // Layer 1 (64 -> 64, in cols [0,64), out [64,128))
  fused_dist_knn<64><<<fgrid, fblk, 0, stream>>>(xh, xl, 0, normsB, idxb);
  pt_gemm<64, 128><<<dim3(128, 2), blk, 0, stream>>>(xh, xl, 0, wb1, wb1 + 8192, b1, Yb, Tb);
  edge_reduce<64, 16><<<ergrid, blk, 0, stream>>>(Yb, Tb, idxb, featA, stats + 512, stats + 768);
  bnrelu_kernel<64, true><<<dim3(512), blk, 0, stream>>>(featA, stats + 512, stats + 768,
      g1, be1, xh, xl, 64, normsC);

  // Layer 2 (64 -> 128, in cols [64,128), out [128,256))
  fused_dist_knn<64><<<fgrid, fblk, 0, stream>>>(xh, xl, 64, normsC, idxb);
  pt_gemm<64, 256><<<dim3(128, 4), blk, 0, stream>>>(xh, xl, 64, wb2, wb2 + 16384, b2, Yb, Tb);
  edge_reduce<128, 16><<<ergrid, blk, 0, stream>>>(Yb, Tb, idxb, featA, stats + 1024, stats + 1280);
  bnrelu_kernel<128, true><<<dim3(1024), blk, 0, stream>>>(featA, stats + 1024, stats + 1280,
      g2, be2, xh, xl, 128, normsD);

  // Layer 3 (128 -> 256, in cols [128,256), out [256,512))
  fused_dist_knn<128><<<fgrid, fblk, 0, stream>>>(xh, xl, 128, normsD, idxb);
  pt_gemm<128, 512><<<dim3(128, 8), blk, 0, stream>>>(xh, xl, 128, wb3, wb3 + 65536, b3, Yb, Tb);
  edge_reduce<256, 16><<<ergrid, blk, 0, stream>>>(Yb, Tb, idxb, featA, stats + 1536, stats + 1792);
  bnrelu_kernel<256, false><<<dim3(2048), blk, 0, stream>>>(featA, stats + 1536, stats + 1792,
      g3, be3, xh, xl, 256, nullptr);

  // Final 1x1 conv + global max pool (single-plane, 2 n-tiles/block)
  final_mfma<<<dim3(16, 16, 8), blk, 0, stream>>>(xh, wfh, outenc);
  decode_kernel<<<dim3(32), blk, 0, stream>>>(outenc, bf, (float*)d_out);
}